// Round 1
// baseline (449.379 us; speedup 1.0000x reference)
//
#include <hip/hip_runtime.h>

#define T_NUM 1024
#define DET_NUM 1024
#define DEG 64
#define E_NUM (T_NUM*DEG)        // 65536
#define TWO_E (2*E_NUM)          // 131072
#define N_NODES (T_NUM+DET_NUM)  // 2048
#define D_IN 512
#define D_EMB 256

// ---------------- node = relu(x @ W_enc + b_enc) ----------------
// 8 rows per block of 256 threads. thread j owns output column j.
__global__ __launch_bounds__(256) void k_encoder(
    const float* __restrict__ x, const float* __restrict__ W,
    const float* __restrict__ b, float* __restrict__ node) {
  __shared__ float xs[8][D_IN];
  const int j = threadIdx.x;
  const int row0 = blockIdx.x * 8;
  for (int i = threadIdx.x; i < 8 * D_IN; i += 256)
    xs[i >> 9][i & 511] = x[(size_t)(row0 + (i >> 9)) * D_IN + (i & 511)];
  __syncthreads();
  float acc[8];
  const float bj = b[j];
#pragma unroll
  for (int r = 0; r < 8; r++) acc[r] = bj;
  for (int k = 0; k < D_IN; k++) {
    const float w = W[k * D_EMB + j];
#pragma unroll
    for (int r = 0; r < 8; r++) acc[r] = fmaf(xs[r][k], w, acc[r]);
  }
#pragma unroll
  for (int r = 0; r < 8; r++)
    node[(size_t)(row0 + r) * D_EMB + j] = fmaxf(acc[r], 0.f);
}

// ---------------- P1=node@W1a[:256], P2=node@W1a[256:], G1/G2 from coords ---
// 4 nodes per block; thread = (node_local, h<64)
__global__ __launch_bounds__(256) void k_pg(
    const float* __restrict__ node, const float* __restrict__ coords,
    const float* __restrict__ W1a, const float* __restrict__ W1g,
    float* __restrict__ P1, float* __restrict__ P2,
    float* __restrict__ G1, float* __restrict__ G2) {
  __shared__ float ns[4][D_EMB];
  const int loc = threadIdx.x >> 6;
  const int h = threadIdx.x & 63;
  const int n = blockIdx.x * 4 + loc;
  for (int i = threadIdx.x; i < 4 * D_EMB; i += 256)
    ns[i >> 8][i & 255] = node[(size_t)(blockIdx.x * 4 + (i >> 8)) * D_EMB + (i & 255)];
  __syncthreads();
  float a1 = 0.f, a2 = 0.f;
  for (int k = 0; k < D_EMB; k++) {
    const float nv = ns[loc][k];
    a1 = fmaf(nv, W1a[k * 64 + h], a1);
    a2 = fmaf(nv, W1a[(D_EMB + k) * 64 + h], a2);
  }
  P1[(size_t)n * 64 + h] = a1;
  P2[(size_t)n * 64 + h] = a2;
  if (h < 16) {
    float g1 = 0.f, g2 = 0.f;
#pragma unroll
    for (int k = 0; k < 4; k++) {
      const float c = coords[(size_t)n * 4 + k];
      g1 = fmaf(c, W1g[k * 16 + h], g1);
      g2 = fmaf(c, W1g[(4 + k) * 16 + h], g2);
    }
    G1[(size_t)n * 16 + h] = g1;
    G2[(size_t)n * 16 + h] = g2;
  }
}

// ---------------- build incoming-edge adjacency (generic, atomic) ----------
__global__ __launch_bounds__(256) void k_adj(
    const int* __restrict__ ei, int* __restrict__ cnt, int* __restrict__ adj) {
  const int e = blockIdx.x * 256 + threadIdx.x;
  if (e >= TWO_E) return;
  const int dn = ei[TWO_E + e];
  const int slot = atomicAdd(&cnt[dn], 1);
  if (slot < 64) adj[dn * 64 + slot] = e;
}

// ---------------- per-edge scalar weight (edge_emb) ----------------
__global__ __launch_bounds__(256) void k_edge(
    const int* __restrict__ ei,
    const float* __restrict__ P1, const float* __restrict__ P2,
    const float* __restrict__ G1, const float* __restrict__ G2,
    const float* __restrict__ b1a, const float* __restrict__ W2a, const float* __restrict__ b2a,
    const float* __restrict__ b1g, const float* __restrict__ W2g, const float* __restrict__ b2g,
    const float* __restrict__ W1f, const float* __restrict__ b1f,
    const float* __restrict__ W2f, const float* __restrict__ b2f,
    float* __restrict__ wE) {
  const int e = blockIdx.x * 256 + threadIdx.x;
  if (e >= TWO_E) return;
  const int s = ei[e], dn = ei[TWO_E + e];
  const float4* p1 = (const float4*)(P1 + (size_t)s * 64);
  const float4* p2 = (const float4*)(P2 + (size_t)dn * 64);
  const float4* b1 = (const float4*)b1a;
  const float4* w2 = (const float4*)W2a;
  float a1 = b2a[0];
#pragma unroll
  for (int i = 0; i < 16; i++) {
    const float4 pa = p1[i], pb = p2[i], bb = b1[i], ww = w2[i];
    a1 += fmaxf(pa.x + pb.x + bb.x, 0.f) * ww.x + fmaxf(pa.y + pb.y + bb.y, 0.f) * ww.y +
          fmaxf(pa.z + pb.z + bb.z, 0.f) * ww.z + fmaxf(pa.w + pb.w + bb.w, 0.f) * ww.w;
  }
  const float4* g1 = (const float4*)(G1 + (size_t)s * 16);
  const float4* g2 = (const float4*)(G2 + (size_t)dn * 16);
  const float4* bg = (const float4*)b1g;
  const float4* wg = (const float4*)W2g;
  float a2 = b2g[0];
#pragma unroll
  for (int i = 0; i < 4; i++) {
    const float4 pa = g1[i], pb = g2[i], bb = bg[i], ww = wg[i];
    a2 += fmaxf(pa.x + pb.x + bb.x, 0.f) * ww.x + fmaxf(pa.y + pb.y + bb.y, 0.f) * ww.y +
          fmaxf(pa.z + pb.z + bb.z, 0.f) * ww.z + fmaxf(pa.w + pb.w + bb.w, 0.f) * ww.w;
  }
  float acc = b2f[0];
#pragma unroll
  for (int j = 0; j < 8; j++) {
    const float h = fmaxf(a1 * W1f[j] + a2 * W1f[8 + j] + b1f[j], 0.f);
    acc = fmaf(h, W2f[j], acc);
  }
  wE[e] = acc;
}

// ---------------- msg[n] = sum over incoming edges of w[e]*node[src] -------
__global__ __launch_bounds__(256) void k_msg(
    const int* __restrict__ ei, const int* __restrict__ cnt, const int* __restrict__ adj,
    const float* __restrict__ wE, const float* __restrict__ node, float* __restrict__ msg) {
  __shared__ float wsh[64];
  __shared__ int ssh[64];
  const int n = blockIdx.x;
  const int tid = threadIdx.x;
  int c = cnt[n];
  c = (c < 64) ? c : 64;
  if (tid < 64 && tid < c) {
    const int e = adj[n * 64 + tid];
    wsh[tid] = wE[e];
    ssh[tid] = ei[e];
  }
  __syncthreads();
  float acc = 0.f;
  for (int i = 0; i < c; i++)
    acc = fmaf(wsh[i], node[(size_t)ssh[i] * D_EMB + tid], acc);
  msg[(size_t)n * D_EMB + tid] = acc;
}

// ---------------- out = relu(node@Wn + msg@Wm + bo) ----------------
__global__ __launch_bounds__(256) void k_out(
    const float* __restrict__ node, const float* __restrict__ msg,
    const float* __restrict__ Wn, const float* __restrict__ Wm,
    const float* __restrict__ bo, float* __restrict__ outE) {
  __shared__ float ns[8][D_EMB];
  __shared__ float ms[8][D_EMB];
  const int j = threadIdx.x;
  const int row0 = blockIdx.x * 8;
  for (int i = threadIdx.x; i < 8 * D_EMB; i += 256) {
    const int r = i >> 8, c = i & 255;
    ns[r][c] = node[(size_t)(row0 + r) * D_EMB + c];
    ms[r][c] = msg[(size_t)(row0 + r) * D_EMB + c];
  }
  __syncthreads();
  float acc[8];
  const float bj = bo[j];
#pragma unroll
  for (int r = 0; r < 8; r++) acc[r] = bj;
  for (int k = 0; k < D_EMB; k++) {
    const float wn = Wn[k * D_EMB + j], wm = Wm[k * D_EMB + j];
#pragma unroll
    for (int r = 0; r < 8; r++) acc[r] += ns[r][k] * wn + ms[r][k] * wm;
  }
#pragma unroll
  for (int r = 0; r < 8; r++)
    outE[(size_t)(row0 + r) * D_EMB + j] = fmaxf(acc[r], 0.f);
}

// ---------------- row norms of outE ----------------
__global__ __launch_bounds__(256) void k_norm(
    const float* __restrict__ outE, float* __restrict__ nrm) {
  const int w = threadIdx.x >> 6, lane = threadIdx.x & 63;
  const int n = blockIdx.x * 4 + w;
  const float* row = outE + (size_t)n * D_EMB;
  float s = 0.f;
  for (int i = lane; i < D_EMB; i += 64) { const float v = row[i]; s = fmaf(v, v, s); }
#pragma unroll
  for (int o = 32; o > 0; o >>= 1) s += __shfl_down(s, o, 64);
  if (lane == 0) nrm[n] = sqrtf(s);
}

// ---------------- cos/iou/aff -> K (and transposed KT with src ids) --------
__global__ __launch_bounds__(256) void k_aff(
    const int* __restrict__ ei, const float* __restrict__ outE, const float* __restrict__ nrm,
    const float* __restrict__ cov,
    const float* __restrict__ W1c, const float* __restrict__ b1c,
    const float* __restrict__ W2c, const float* __restrict__ b2c,
    float* __restrict__ K, float* __restrict__ KT, int* __restrict__ KTsrc) {
  const int e = blockIdx.x * 256 + threadIdx.x;
  if (e >= E_NUM) return;
  const int s = ei[e], dn = ei[TWO_E + e];
  const float4* oa = (const float4*)(outE + (size_t)s * D_EMB);
  const float4* ob = (const float4*)(outE + (size_t)dn * D_EMB);
  float dot = 0.f;
#pragma unroll 8
  for (int i = 0; i < 64; i++) {
    const float4 a = oa[i], b = ob[i];
    dot += a.x * b.x + a.y * b.y + a.z * b.z + a.w * b.w;
  }
  const float cosv = dot / fmaxf(nrm[s] * nrm[dn], 1e-6f);
  const float4 A = ((const float4*)cov)[s];
  const float4 B = ((const float4*)cov)[dn];
  const float ltx = fmaxf(A.x, B.x), lty = fmaxf(A.y, B.y);
  const float rbx = fminf(A.z, B.z), rby = fminf(A.w, B.w);
  const float wx = fmaxf(rbx - ltx, 0.f), wy = fmaxf(rby - lty, 0.f);
  const float inter = wx * wy;
  const float areaA = (A.z - A.x) * (A.w - A.y);
  const float areaB = (B.z - B.x) * (B.w - B.y);
  const float iou = inter / (areaA + areaB - inter + 1e-9f);
  float aff = b2c[0];
#pragma unroll
  for (int j = 0; j < 8; j++) {
    const float h = fmaxf(cosv * W1c[j] + iou * W1c[8 + j] + b1c[j], 0.f);
    aff = fmaf(h, W2c[j], aff);
  }
  const float Kv = expf(aff * 5.0f);
  K[e] = Kv;
  const int d = dn - T_NUM;
  const int off = e & 63;                   // unique slot per column (13 coprime to 1024)
  KT[d * 64 + off] = Kv;
  KTsrc[d * 64 + off] = s;
}

// ---------------- Sinkhorn on diag(u)*M0*diag(v), single workgroup ---------
// M0: rows 0..1023 have 64 K-entries + slack at col 1024; row/col 1024 all slack.
__global__ __launch_bounds__(1024) void k_sinkhorn(
    const float* __restrict__ K, const float* __restrict__ KT,
    const int* __restrict__ KTsrc, float* __restrict__ ug, float* __restrict__ vg) {
  __shared__ float u[1025];
  __shared__ float v[1025];
  __shared__ float red[16];
  const int tid = threadIdx.x;
  const int lane = tid & 63, wid = tid >> 6;
  u[tid] = 1.f; v[tid] = 1.f;
  if (tid == 0) { u[1024] = 1.f; v[1024] = 1.f; }
  __syncthreads();
  const float slack = expf(-1.0f);  // exp(SLACK*LAM)
  const float4* K4 = (const float4*)(K + (size_t)tid * 64);
  const float4* KT4 = (const float4*)(KT + (size_t)tid * 64);
  const int4* KS4 = (const int4*)(KTsrc + (size_t)tid * 64);
  const int base = 13 * tid;
  for (int it = 0; it < 8; ++it) {
    // ---- row normalize: s_i = sum_j M0_ij v_j ; u_i /= (u_i*s_i + eps)
    float s = slack * v[1024];
#pragma unroll 4
    for (int i = 0; i < 16; i++) {
      const float4 kk = K4[i];
      const int o = base + 4 * i;
      s = fmaf(kk.x, v[o & 1023], s);
      s = fmaf(kk.y, v[(o + 1) & 1023], s);
      s = fmaf(kk.z, v[(o + 2) & 1023], s);
      s = fmaf(kk.w, v[(o + 3) & 1023], s);
    }
    float rv = v[tid];
#pragma unroll
    for (int o = 32; o > 0; o >>= 1) rv += __shfl_down(rv, o, 64);
    if (lane == 0) red[wid] = rv;
    __syncthreads();
    if (tid == 0) {
      float sv = 0.f;
      for (int i = 0; i < 16; i++) sv += red[i];
      sv += v[1024];
      const float u4 = u[1024];
      u[1024] = u4 / (u4 * slack * sv + 1e-9f);
    }
    const float ui = u[tid];
    u[tid] = ui / (ui * s + 1e-9f);
    __syncthreads();
    // ---- col normalize: t_j = sum_i M0_ij u_i ; v_j /= (v_j*t_j + eps)
    float t = slack * u[1024];
#pragma unroll 4
    for (int i = 0; i < 16; i++) {
      const float4 kk = KT4[i];
      const int4 s4 = KS4[i];
      t = fmaf(kk.x, u[s4.x], t);
      t = fmaf(kk.y, u[s4.y], t);
      t = fmaf(kk.z, u[s4.z], t);
      t = fmaf(kk.w, u[s4.w], t);
    }
    float ru = u[tid];
#pragma unroll
    for (int o = 32; o > 0; o >>= 1) ru += __shfl_down(ru, o, 64);
    if (lane == 0) red[wid] = ru;
    __syncthreads();
    if (tid == 0) {
      float su = 0.f;
      for (int i = 0; i < 16; i++) su += red[i];
      su += u[1024];
      const float v4 = v[1024];
      v[1024] = v4 / (v4 * slack * su + 1e-9f);
    }
    const float vj = v[tid];
    v[tid] = vj / (vj * t + 1e-9f);
    __syncthreads();
  }
  ug[tid] = u[tid];
  vg[tid] = v[tid];
  if (tid == 0) { ug[1024] = u[1024]; vg[1024] = v[1024]; }
}

// ---------------- final scatter: out[t,d] = u[t]*K[e]*v[d]; scalars --------
__global__ __launch_bounds__(256) void k_final(
    const int* __restrict__ ei, const float* __restrict__ K,
    const float* __restrict__ ug, const float* __restrict__ vg,
    float* __restrict__ out) {
  const int e = blockIdx.x * 256 + threadIdx.x;
  if (e >= E_NUM) return;
  const int t = ei[e];
  const int d = ei[TWO_E + e] - T_NUM;
  out[(size_t)t * DET_NUM + d] = ug[t] * K[e] * vg[d];
  if (e == 0) {
    out[(size_t)2 * T_NUM * DET_NUM] = 1024.0f;      // det_num
    out[(size_t)2 * T_NUM * DET_NUM + 1] = 1024.0f;  // tracklet_num
  }
}

extern "C" void kernel_launch(void* const* d_in, const int* in_sizes, int n_in,
                              void* d_out, int out_size, void* d_ws, size_t ws_size,
                              hipStream_t stream) {
  const float* x      = (const float*)d_in[0];
  const float* coords = (const float*)d_in[1];
  const float* cov    = (const float*)d_in[2];
  const float* gt     = (const float*)d_in[3];
  const int*   ei     = (const int*)d_in[4];
  const float* W_enc  = (const float*)d_in[5];
  const float* b_enc  = (const float*)d_in[6];
  const float* W1a    = (const float*)d_in[7];
  const float* b1a    = (const float*)d_in[8];
  const float* W2a    = (const float*)d_in[9];
  const float* b2a    = (const float*)d_in[10];
  const float* W1g    = (const float*)d_in[11];
  const float* b1g    = (const float*)d_in[12];
  const float* W2g    = (const float*)d_in[13];
  const float* b2g    = (const float*)d_in[14];
  const float* W1f    = (const float*)d_in[15];
  const float* b1f    = (const float*)d_in[16];
  const float* W2f    = (const float*)d_in[17];
  const float* b2f    = (const float*)d_in[18];
  const float* Wn     = (const float*)d_in[19];
  const float* Wm     = (const float*)d_in[20];
  const float* bo     = (const float*)d_in[21];
  const float* W1c    = (const float*)d_in[22];
  const float* b1c    = (const float*)d_in[23];
  const float* W2c    = (const float*)d_in[24];
  const float* b2c    = (const float*)d_in[25];

  char* ws = (char*)d_ws;
  size_t off = 0;
  auto alloc = [&](size_t bytes) {
    char* p = ws + off;
    off = (off + bytes + 255) & ~(size_t)255;
    return p;
  };
  float* node  = (float*)alloc((size_t)N_NODES * D_EMB * 4);
  float* P1    = (float*)alloc((size_t)N_NODES * 64 * 4);
  float* P2    = (float*)alloc((size_t)N_NODES * 64 * 4);
  float* G1    = (float*)alloc((size_t)N_NODES * 16 * 4);
  float* G2    = (float*)alloc((size_t)N_NODES * 16 * 4);
  float* wE    = (float*)alloc((size_t)TWO_E * 4);
  float* msg   = (float*)alloc((size_t)N_NODES * D_EMB * 4);
  float* outE  = (float*)alloc((size_t)N_NODES * D_EMB * 4);
  float* nrm   = (float*)alloc((size_t)N_NODES * 4);
  float* K     = (float*)alloc((size_t)E_NUM * 4);
  float* KT    = (float*)alloc((size_t)E_NUM * 4);
  int*   KTsrc = (int*)alloc((size_t)E_NUM * 4);
  float* ug    = (float*)alloc(1025 * 4);
  float* vg    = (float*)alloc(1025 * 4);
  int*   cnt   = (int*)alloc((size_t)N_NODES * 4);
  int*   adj   = (int*)alloc((size_t)N_NODES * 64 * 4);
  float* out   = (float*)d_out;

  hipMemsetAsync(cnt, 0, (size_t)N_NODES * 4, stream);
  hipMemsetAsync(out, 0, (size_t)T_NUM * DET_NUM * 4, stream);
  hipMemcpyAsync(out + (size_t)T_NUM * DET_NUM, gt, (size_t)T_NUM * DET_NUM * 4,
                 hipMemcpyDeviceToDevice, stream);

  k_encoder<<<N_NODES / 8, 256, 0, stream>>>(x, W_enc, b_enc, node);
  k_pg<<<N_NODES / 4, 256, 0, stream>>>(node, coords, W1a, W1g, P1, P2, G1, G2);
  k_adj<<<TWO_E / 256, 256, 0, stream>>>(ei, cnt, adj);
  k_edge<<<TWO_E / 256, 256, 0, stream>>>(ei, P1, P2, G1, G2, b1a, W2a, b2a,
                                          b1g, W2g, b2g, W1f, b1f, W2f, b2f, wE);
  k_msg<<<N_NODES, 256, 0, stream>>>(ei, cnt, adj, wE, node, msg);
  k_out<<<N_NODES / 8, 256, 0, stream>>>(node, msg, Wn, Wm, bo, outE);
  k_norm<<<N_NODES / 4, 256, 0, stream>>>(outE, nrm);
  k_aff<<<E_NUM / 256, 256, 0, stream>>>(ei, outE, nrm, cov, W1c, b1c, W2c, b2c,
                                         K, KT, KTsrc);
  k_sinkhorn<<<1, 1024, 0, stream>>>(K, KT, KTsrc, ug, vg);
  k_final<<<E_NUM / 256, 256, 0, stream>>>(ei, K, ug, vg, out);
}

// Round 2
// 367.109 us; speedup vs baseline: 1.2241x; 1.2241x over previous
//
#include <hip/hip_runtime.h>

#define T_NUM 1024
#define DET_NUM 1024
#define E_NUM 65536
#define TWO_E 131072
#define N_NODES 2048
#define D_IN 512
#define D_EMB 256

// ======== fused encoder + P1/P2/G1/G2 precompute ========
// node = relu(x@W_enc+b); P1=node@W1a[:256]; P2=node@W1a[256:]; G from coords
__global__ __launch_bounds__(256) void k_enc_pg(
    const float* __restrict__ x, const float* __restrict__ W,
    const float* __restrict__ b, const float* __restrict__ coords,
    const float* __restrict__ W1a, const float* __restrict__ W1g,
    float* __restrict__ node, float* __restrict__ P1, float* __restrict__ P2,
    float* __restrict__ G1, float* __restrict__ G2) {
  __shared__ float xs[8][D_IN];
  __shared__ float ns[8][D_EMB];
  const int j = threadIdx.x;
  const int row0 = blockIdx.x * 8;
  for (int i = j; i < 8 * D_IN; i += 256)
    xs[i >> 9][i & 511] = x[(size_t)(row0 + (i >> 9)) * D_IN + (i & 511)];
  __syncthreads();
  float acc[8];
  const float bj = b[j];
#pragma unroll
  for (int r = 0; r < 8; r++) acc[r] = bj;
  for (int k = 0; k < D_IN; k++) {
    const float w = W[k * D_EMB + j];
#pragma unroll
    for (int r = 0; r < 8; r++) acc[r] = fmaf(xs[r][k], w, acc[r]);
  }
#pragma unroll
  for (int r = 0; r < 8; r++) {
    const float v = fmaxf(acc[r], 0.f);
    node[(size_t)(row0 + r) * D_EMB + j] = v;
    ns[r][j] = v;
  }
  __syncthreads();
#pragma unroll
  for (int p = 0; p < 2; p++) {
    const int it = j + p * 256;
    const int r = it >> 6, h = it & 63;
    float a1 = 0.f, a2 = 0.f;
    for (int k = 0; k < D_EMB; k++) {
      const float nv = ns[r][k];
      a1 = fmaf(nv, W1a[k * 64 + h], a1);
      a2 = fmaf(nv, W1a[(D_EMB + k) * 64 + h], a2);
    }
    P1[(size_t)(row0 + r) * 64 + h] = a1;
    P2[(size_t)(row0 + r) * 64 + h] = a2;
  }
  if (j < 128) {
    const int r = j >> 4, h = j & 15;
    const int n = row0 + r;
    float g1 = 0.f, g2 = 0.f;
#pragma unroll
    for (int k = 0; k < 4; k++) {
      const float c = coords[(size_t)n * 4 + k];
      g1 = fmaf(c, W1g[k * 16 + h], g1);
      g2 = fmaf(c, W1g[(4 + k) * 16 + h], g2);
    }
    G1[(size_t)n * 16 + h] = g1;
    G2[(size_t)n * 16 + h] = g2;
  }
}

// ======== fused adjacency build + per-edge scalar weight ========
__global__ __launch_bounds__(256) void k_adj_edge(
    const int* __restrict__ ei, int* __restrict__ cnt, int* __restrict__ adj,
    const float* __restrict__ P1, const float* __restrict__ P2,
    const float* __restrict__ G1, const float* __restrict__ G2,
    const float* __restrict__ b1a, const float* __restrict__ W2a, const float* __restrict__ b2a,
    const float* __restrict__ b1g, const float* __restrict__ W2g, const float* __restrict__ b2g,
    const float* __restrict__ W1f, const float* __restrict__ b1f,
    const float* __restrict__ W2f, const float* __restrict__ b2f,
    float* __restrict__ wE) {
  const int e = blockIdx.x * 256 + threadIdx.x;
  if (e >= TWO_E) return;
  const int s = ei[e], dn = ei[TWO_E + e];
  const int slot = atomicAdd(&cnt[dn], 1);
  if (slot < 64) adj[dn * 64 + slot] = e;
  const float4* p1 = (const float4*)(P1 + (size_t)s * 64);
  const float4* p2 = (const float4*)(P2 + (size_t)dn * 64);
  const float4* b1 = (const float4*)b1a;
  const float4* w2 = (const float4*)W2a;
  float a1 = b2a[0];
#pragma unroll
  for (int i = 0; i < 16; i++) {
    const float4 pa = p1[i], pb = p2[i], bb = b1[i], ww = w2[i];
    a1 += fmaxf(pa.x + pb.x + bb.x, 0.f) * ww.x + fmaxf(pa.y + pb.y + bb.y, 0.f) * ww.y +
          fmaxf(pa.z + pb.z + bb.z, 0.f) * ww.z + fmaxf(pa.w + pb.w + bb.w, 0.f) * ww.w;
  }
  const float4* g1 = (const float4*)(G1 + (size_t)s * 16);
  const float4* g2 = (const float4*)(G2 + (size_t)dn * 16);
  const float4* bg = (const float4*)b1g;
  const float4* wg = (const float4*)W2g;
  float a2 = b2g[0];
#pragma unroll
  for (int i = 0; i < 4; i++) {
    const float4 pa = g1[i], pb = g2[i], bb = bg[i], ww = wg[i];
    a2 += fmaxf(pa.x + pb.x + bb.x, 0.f) * ww.x + fmaxf(pa.y + pb.y + bb.y, 0.f) * ww.y +
          fmaxf(pa.z + pb.z + bb.z, 0.f) * ww.z + fmaxf(pa.w + pb.w + bb.w, 0.f) * ww.w;
  }
  float acc = b2f[0];
#pragma unroll
  for (int j = 0; j < 8; j++) {
    const float h = fmaxf(a1 * W1f[j] + a2 * W1f[8 + j] + b1f[j], 0.f);
    acc = fmaf(h, W2f[j], acc);
  }
  wE[e] = acc;
}

// ======== msg[n] = sum_{incoming e} wE[e]*node[src[e]] ========
__global__ __launch_bounds__(256) void k_msg(
    const int* __restrict__ ei, const int* __restrict__ cnt, const int* __restrict__ adj,
    const float* __restrict__ wE, const float* __restrict__ node, float* __restrict__ msg) {
  __shared__ float wsh[64];
  __shared__ int ssh[64];
  const int n = blockIdx.x;
  const int tid = threadIdx.x;
  int c = cnt[n];
  c = (c < 64) ? c : 64;
  if (tid < 64 && tid < c) {
    const int e = adj[n * 64 + tid];
    wsh[tid] = wE[e];
    ssh[tid] = ei[e];
  }
  __syncthreads();
  float acc = 0.f;
  for (int i = 0; i < c; i++)
    acc = fmaf(wsh[i], node[(size_t)ssh[i] * D_EMB + tid], acc);
  msg[(size_t)n * D_EMB + tid] = acc;
}

// ======== out = relu(node@Wn + msg@Wm + bo) fused with row norms ========
__global__ __launch_bounds__(256) void k_out_norm(
    const float* __restrict__ node, const float* __restrict__ msg,
    const float* __restrict__ Wn, const float* __restrict__ Wm,
    const float* __restrict__ bo, float* __restrict__ outE, float* __restrict__ nrm) {
  __shared__ float ns[8][D_EMB];
  __shared__ float ms[8][D_EMB];
  __shared__ float redn[4][8];
  const int j = threadIdx.x;
  const int lane = j & 63, wid = j >> 6;
  const int row0 = blockIdx.x * 8;
  for (int i = j; i < 8 * D_EMB; i += 256) {
    const int r = i >> 8, c = i & 255;
    ns[r][c] = node[(size_t)(row0 + r) * D_EMB + c];
    ms[r][c] = msg[(size_t)(row0 + r) * D_EMB + c];
  }
  __syncthreads();
  float acc[8];
  const float bj = bo[j];
#pragma unroll
  for (int r = 0; r < 8; r++) acc[r] = bj;
  for (int k = 0; k < D_EMB; k++) {
    const float wn = Wn[k * D_EMB + j], wm = Wm[k * D_EMB + j];
#pragma unroll
    for (int r = 0; r < 8; r++) acc[r] += ns[r][k] * wn + ms[r][k] * wm;
  }
#pragma unroll
  for (int r = 0; r < 8; r++) {
    acc[r] = fmaxf(acc[r], 0.f);
    outE[(size_t)(row0 + r) * D_EMB + j] = acc[r];
  }
#pragma unroll
  for (int r = 0; r < 8; r++) {
    float sq = acc[r] * acc[r];
#pragma unroll
    for (int o = 32; o > 0; o >>= 1) sq += __shfl_down(sq, o, 64);
    if (lane == 0) redn[wid][r] = sq;
  }
  __syncthreads();
  if (j < 8)
    nrm[row0 + j] = sqrtf(redn[0][j] + redn[1][j] + redn[2][j] + redn[3][j]);
}

// ======== affinity -> banded kernel buffers (permuted row space) ========
// t' = 13*t mod 1024 ; row t' window covers cols [t', t'+63]
// Kbp[t'][  (t'&3) + m        ] = K  (m = (d - t') mod 1024, < 64)
// KTfp[d ][ ((d+961)&3) + 63-m] = K  (col d window covers rows [d-63, d])
__global__ __launch_bounds__(256) void k_aff(
    const int* __restrict__ ei, const float* __restrict__ outE, const float* __restrict__ nrm,
    const float* __restrict__ cov,
    const float* __restrict__ W1c, const float* __restrict__ b1c,
    const float* __restrict__ W2c, const float* __restrict__ b2c,
    float* __restrict__ Kbp, float* __restrict__ KTfp) {
  const int e = blockIdx.x * 256 + threadIdx.x;
  if (e >= E_NUM) return;
  const int s = ei[e], dn = ei[TWO_E + e];
  const float4* oa = (const float4*)(outE + (size_t)s * D_EMB);
  const float4* ob = (const float4*)(outE + (size_t)dn * D_EMB);
  float dot = 0.f;
#pragma unroll 8
  for (int i = 0; i < 64; i++) {
    const float4 a = oa[i], bq = ob[i];
    dot += a.x * bq.x + a.y * bq.y + a.z * bq.z + a.w * bq.w;
  }
  const float cosv = dot / fmaxf(nrm[s] * nrm[dn], 1e-6f);
  const float4 A = ((const float4*)cov)[s];
  const float4 B = ((const float4*)cov)[dn];
  const float ltx = fmaxf(A.x, B.x), lty = fmaxf(A.y, B.y);
  const float rbx = fminf(A.z, B.z), rby = fminf(A.w, B.w);
  const float wx = fmaxf(rbx - ltx, 0.f), wy = fmaxf(rby - lty, 0.f);
  const float inter = wx * wy;
  const float areaA = (A.z - A.x) * (A.w - A.y);
  const float areaB = (B.z - B.x) * (B.w - B.y);
  const float iou = inter / (areaA + areaB - inter + 1e-9f);
  float aff = b2c[0];
#pragma unroll
  for (int j = 0; j < 8; j++) {
    const float h = fmaxf(cosv * W1c[j] + iou * W1c[8 + j] + b1c[j], 0.f);
    aff = fmaf(h, W2c[j], aff);
  }
  const float Kv = __expf(aff * 5.0f);
  const int d = dn - T_NUM;
  const int tp = (13 * s) & 1023;
  const int m = (d - tp) & 1023;            // == e & 63 for this graph
  Kbp[tp * 68 + (tp & 3) + m] = Kv;
  const int s0 = (d + 961) & 1023;          // col-window start (d-63 mod 1024)
  KTfp[d * 68 + (s0 & 3) + 63 - m] = Kv;
}

// ======== Sinkhorn: register-resident bf16 K bands, vectorized LDS ========
__device__ __forceinline__ unsigned bf16r(float x) {
  const unsigned u = __float_as_uint(x);
  return (u + 0x7fffu + ((u >> 16) & 1u)) >> 16;  // RNE
}
__device__ __forceinline__ float bflo(unsigned p) { return __uint_as_float(p << 16); }
__device__ __forceinline__ float bfhi(unsigned p) { return __uint_as_float(p & 0xffff0000u); }

__global__ __launch_bounds__(1024) void k_sinkhorn(
    const float* __restrict__ Kbp, const float* __restrict__ KTfp,
    float* __restrict__ ug, float* __restrict__ vg) {
  __shared__ float u_lds[1092];   // replicated: [1024+i] = [i] for i<68
  __shared__ float v_lds[1092];
  __shared__ float red_u[16];
  __shared__ float red_v[16];
  const int tid = threadIdx.x;
  const int lane = tid & 63, wid = tid >> 6;
  unsigned kb[34], kc[34];
  {
    const float4* s1 = (const float4*)(Kbp + (size_t)tid * 68);
    const float4* s2 = (const float4*)(KTfp + (size_t)tid * 68);
#pragma unroll
    for (int c = 0; c < 17; c++) {
      const float4 f = s1[c];
      kb[2 * c] = bf16r(f.x) | (bf16r(f.y) << 16);
      kb[2 * c + 1] = bf16r(f.z) | (bf16r(f.w) << 16);
    }
#pragma unroll
    for (int c = 0; c < 17; c++) {
      const float4 f = s2[c];
      kc[2 * c] = bf16r(f.x) | (bf16r(f.y) << 16);
      kc[2 * c + 1] = bf16r(f.z) | (bf16r(f.w) << 16);
    }
  }
  float u_own = 1.f, v_own = 1.f, u_sl = 1.f, v_sl = 1.f;
  v_lds[tid] = 1.f;
  if (tid < 68) v_lds[1024 + tid] = 1.f;
  if (tid < 16) red_v[tid] = 64.f;
  const float slack = 0.36787944117144233f;  // exp(SLACK*LAM) = exp(-1)
  const int qa = tid >> 2;
  const int qc = ((tid + 961) & 1023) >> 2;
  __syncthreads();
#pragma unroll 1
  for (int it = 0; it < 8; ++it) {
    // ---- row phase: s_i = K_i . v_window + slack*v_slack
    float s0 = 0.f, s1a = 0.f;
    const float4* vq = (const float4*)v_lds;
#pragma unroll
    for (int c = 0; c < 17; c++) {
      const float4 v4 = vq[qa + c];
      const unsigned p0 = kb[2 * c], p1 = kb[2 * c + 1];
      s0 = fmaf(bflo(p0), v4.x, s0);
      s0 = fmaf(bfhi(p0), v4.y, s0);
      s1a = fmaf(bflo(p1), v4.z, s1a);
      s1a = fmaf(bfhi(p1), v4.w, s1a);
    }
    float sumv = 0.f;
#pragma unroll
    for (int i = 0; i < 16; i++) sumv += red_v[i];
    const float s = s0 + s1a + slack * v_sl;
    const float unew = u_own / (u_own * s + 1e-9f);
    u_sl = u_sl / (u_sl * slack * (sumv + v_sl) + 1e-9f);
    u_own = unew;
    u_lds[tid] = unew;
    if (tid < 68) u_lds[1024 + tid] = unew;
    float r = unew;
#pragma unroll
    for (int o = 32; o > 0; o >>= 1) r += __shfl_down(r, o, 64);
    if (lane == 0) red_u[wid] = r;
    __syncthreads();
    // ---- col phase: t_j = KT_j . u_window + slack*u_slack
    float t0 = 0.f, t1a = 0.f;
    const float4* uq = (const float4*)u_lds;
#pragma unroll
    for (int c = 0; c < 17; c++) {
      const float4 u4 = uq[qc + c];
      const unsigned p0 = kc[2 * c], p1 = kc[2 * c + 1];
      t0 = fmaf(bflo(p0), u4.x, t0);
      t0 = fmaf(bfhi(p0), u4.y, t0);
      t1a = fmaf(bflo(p1), u4.z, t1a);
      t1a = fmaf(bfhi(p1), u4.w, t1a);
    }
    float sumu = 0.f;
#pragma unroll
    for (int i = 0; i < 16; i++) sumu += red_u[i];
    const float t = t0 + t1a + slack * u_sl;
    const float vnew = v_own / (v_own * t + 1e-9f);
    v_sl = v_sl / (v_sl * slack * (sumu + u_sl) + 1e-9f);
    v_own = vnew;
    v_lds[tid] = vnew;
    if (tid < 68) v_lds[1024 + tid] = vnew;
    float rr = vnew;
#pragma unroll
    for (int o = 32; o > 0; o >>= 1) rr += __shfl_down(rr, o, 64);
    if (lane == 0) red_v[wid] = rr;
    __syncthreads();
  }
  ug[tid] = u_own;   // indexed by t' (permuted row space)
  vg[tid] = v_own;   // indexed by d
}

// ======== dense final write: out[t][d] = u[t']*K*v[d] (0 off-band) ========
__global__ __launch_bounds__(256) void k_final(
    const float* __restrict__ Kbp, const float* __restrict__ ug,
    const float* __restrict__ vg, float* __restrict__ out) {
  const int t = blockIdx.x;
  const int tp = (13 * t) & 1023;
  const float u = ug[tp];
  const float* krow = Kbp + (size_t)tp * 68 + (tp & 3);
  const int d0 = threadIdx.x * 4;
  const float4 v4 = ((const float4*)vg)[threadIdx.x];
  float4 o4;
  const int m0 = (d0 - tp) & 1023;
  const int m1 = (d0 + 1 - tp) & 1023;
  const int m2 = (d0 + 2 - tp) & 1023;
  const int m3 = (d0 + 3 - tp) & 1023;
  o4.x = (m0 < 64) ? u * krow[m0] * v4.x : 0.f;
  o4.y = (m1 < 64) ? u * krow[m1] * v4.y : 0.f;
  o4.z = (m2 < 64) ? u * krow[m2] * v4.z : 0.f;
  o4.w = (m3 < 64) ? u * krow[m3] * v4.w : 0.f;
  ((float4*)out)[(size_t)t * 256 + threadIdx.x] = o4;
  if (t == 0 && threadIdx.x == 0) {
    out[(size_t)2 * T_NUM * DET_NUM] = 1024.0f;      // det_num
    out[(size_t)2 * T_NUM * DET_NUM + 1] = 1024.0f;  // tracklet_num
  }
}

extern "C" void kernel_launch(void* const* d_in, const int* in_sizes, int n_in,
                              void* d_out, int out_size, void* d_ws, size_t ws_size,
                              hipStream_t stream) {
  const float* x      = (const float*)d_in[0];
  const float* coords = (const float*)d_in[1];
  const float* cov    = (const float*)d_in[2];
  const float* gt     = (const float*)d_in[3];
  const int*   ei     = (const int*)d_in[4];
  const float* W_enc  = (const float*)d_in[5];
  const float* b_enc  = (const float*)d_in[6];
  const float* W1a    = (const float*)d_in[7];
  const float* b1a    = (const float*)d_in[8];
  const float* W2a    = (const float*)d_in[9];
  const float* b2a    = (const float*)d_in[10];
  const float* W1g    = (const float*)d_in[11];
  const float* b1g    = (const float*)d_in[12];
  const float* W2g    = (const float*)d_in[13];
  const float* b2g    = (const float*)d_in[14];
  const float* W1f    = (const float*)d_in[15];
  const float* b1f    = (const float*)d_in[16];
  const float* W2f    = (const float*)d_in[17];
  const float* b2f    = (const float*)d_in[18];
  const float* Wn     = (const float*)d_in[19];
  const float* Wm     = (const float*)d_in[20];
  const float* bo     = (const float*)d_in[21];
  const float* W1c    = (const float*)d_in[22];
  const float* b1c    = (const float*)d_in[23];
  const float* W2c    = (const float*)d_in[24];
  const float* b2c    = (const float*)d_in[25];

  char* ws = (char*)d_ws;
  size_t off = 0;
  auto alloc = [&](size_t bytes) {
    char* p = ws + off;
    off = (off + bytes + 255) & ~(size_t)255;
    return p;
  };
  float* node  = (float*)alloc((size_t)N_NODES * D_EMB * 4);
  float* P1    = (float*)alloc((size_t)N_NODES * 64 * 4);
  float* P2    = (float*)alloc((size_t)N_NODES * 64 * 4);
  float* G1    = (float*)alloc((size_t)N_NODES * 16 * 4);
  float* G2    = (float*)alloc((size_t)N_NODES * 16 * 4);
  float* wE    = (float*)alloc((size_t)TWO_E * 4);
  float* msg   = (float*)alloc((size_t)N_NODES * D_EMB * 4);
  float* outE  = (float*)alloc((size_t)N_NODES * D_EMB * 4);
  float* nrm   = (float*)alloc((size_t)N_NODES * 4);
  float* Kbp   = (float*)alloc((size_t)1024 * 68 * 4);   // 278528 B, 256-mult
  float* KTfp  = (float*)alloc((size_t)1024 * 68 * 4);   // contiguous w/ Kbp
  float* ug    = (float*)alloc(1024 * 4);
  float* vg    = (float*)alloc(1024 * 4);
  int*   cnt   = (int*)alloc((size_t)N_NODES * 4);
  int*   adj   = (int*)alloc((size_t)N_NODES * 64 * 4);
  float* out   = (float*)d_out;

  hipMemsetAsync(cnt, 0, (size_t)N_NODES * 4, stream);
  hipMemsetAsync(Kbp, 0, (size_t)2 * 1024 * 68 * 4, stream);  // Kbp+KTfp pads
  hipMemcpyAsync(out + (size_t)T_NUM * DET_NUM, gt, (size_t)T_NUM * DET_NUM * 4,
                 hipMemcpyDeviceToDevice, stream);

  k_enc_pg<<<N_NODES / 8, 256, 0, stream>>>(x, W_enc, b_enc, coords, W1a, W1g,
                                            node, P1, P2, G1, G2);
  k_adj_edge<<<TWO_E / 256, 256, 0, stream>>>(ei, cnt, adj, P1, P2, G1, G2,
                                              b1a, W2a, b2a, b1g, W2g, b2g,
                                              W1f, b1f, W2f, b2f, wE);
  k_msg<<<N_NODES, 256, 0, stream>>>(ei, cnt, adj, wE, node, msg);
  k_out_norm<<<N_NODES / 8, 256, 0, stream>>>(node, msg, Wn, Wm, bo, outE, nrm);
  k_aff<<<E_NUM / 256, 256, 0, stream>>>(ei, outE, nrm, cov, W1c, b1c, W2c, b2c,
                                         Kbp, KTfp);
  k_sinkhorn<<<1, 1024, 0, stream>>>(Kbp, KTfp, ug, vg);
  k_final<<<T_NUM, 256, 0, stream>>>(Kbp, ug, vg, out);
}

// Round 3
// 334.699 us; speedup vs baseline: 1.3426x; 1.0968x over previous
//
#include <hip/hip_runtime.h>

#define T_NUM 1024
#define DET_NUM 1024
#define E_NUM 65536
#define TWO_E 131072
#define N_NODES 2048
#define D_IN 512
#define D_EMB 256

// ======== fused encoder + P1/P2/G1/G2 precompute ========
// node = relu(x@W_enc+b); P1=node@W1a[:256]; P2=node@W1a[256:]; G from coords
// x rows are read with wave-uniform addresses (scalar-load path); W vector.
__global__ __launch_bounds__(256) void k_enc_pg(
    const float* __restrict__ x, const float* __restrict__ W,
    const float* __restrict__ b, const float* __restrict__ coords,
    const float* __restrict__ W1a, const float* __restrict__ W1g,
    float* __restrict__ node, float* __restrict__ P1, float* __restrict__ P2,
    float* __restrict__ G1, float* __restrict__ G2) {
  __shared__ __align__(16) float ns[8][D_EMB];
  const int j = threadIdx.x;
  const int row0 = blockIdx.x * 8;
  float acc[8];
  const float bj = b[j];
#pragma unroll
  for (int r = 0; r < 8; r++) acc[r] = bj;
  const float* xr = x + (size_t)row0 * D_IN;
  for (int k = 0; k < D_IN; k += 4) {
    const float w0 = W[(k + 0) * D_EMB + j];
    const float w1 = W[(k + 1) * D_EMB + j];
    const float w2 = W[(k + 2) * D_EMB + j];
    const float w3 = W[(k + 3) * D_EMB + j];
#pragma unroll
    for (int r = 0; r < 8; r++) {
      const float4 xv = *reinterpret_cast<const float4*>(xr + (size_t)r * D_IN + k);
      acc[r] = fmaf(xv.x, w0, acc[r]);
      acc[r] = fmaf(xv.y, w1, acc[r]);
      acc[r] = fmaf(xv.z, w2, acc[r]);
      acc[r] = fmaf(xv.w, w3, acc[r]);
    }
  }
#pragma unroll
  for (int r = 0; r < 8; r++) {
    const float v = fmaxf(acc[r], 0.f);
    node[(size_t)(row0 + r) * D_EMB + j] = v;
    ns[r][j] = v;
  }
  __syncthreads();
#pragma unroll
  for (int p = 0; p < 2; p++) {
    const int it = j + p * 256;
    const int r = it >> 6, h = it & 63;
    float a1 = 0.f, a2 = 0.f;
    for (int k = 0; k < D_EMB; k += 4) {
      const float4 nv = *reinterpret_cast<const float4*>(&ns[r][k]);
      a1 = fmaf(nv.x, W1a[(k + 0) * 64 + h], a1);
      a1 = fmaf(nv.y, W1a[(k + 1) * 64 + h], a1);
      a1 = fmaf(nv.z, W1a[(k + 2) * 64 + h], a1);
      a1 = fmaf(nv.w, W1a[(k + 3) * 64 + h], a1);
      a2 = fmaf(nv.x, W1a[(D_EMB + k + 0) * 64 + h], a2);
      a2 = fmaf(nv.y, W1a[(D_EMB + k + 1) * 64 + h], a2);
      a2 = fmaf(nv.z, W1a[(D_EMB + k + 2) * 64 + h], a2);
      a2 = fmaf(nv.w, W1a[(D_EMB + k + 3) * 64 + h], a2);
    }
    P1[(size_t)(row0 + r) * 64 + h] = a1;
    P2[(size_t)(row0 + r) * 64 + h] = a2;
  }
  if (j < 128) {
    const int r = j >> 4, h = j & 15;
    const int n = row0 + r;
    float g1 = 0.f, g2 = 0.f;
#pragma unroll
    for (int k = 0; k < 4; k++) {
      const float c = coords[(size_t)n * 4 + k];
      g1 = fmaf(c, W1g[k * 16 + h], g1);
      g2 = fmaf(c, W1g[(4 + k) * 16 + h], g2);
    }
    G1[(size_t)n * 16 + h] = g1;
    G2[(size_t)n * 16 + h] = g2;
  }
}

// ======== per-edge scalar weight (analytic edge structure, no atomics) =====
// e <  E: src = t=e>>6,          dst = T + (13t+o)%1024
// e >= E: src = T+(13t+o)%1024,  dst = t   (t=(e-E)>>6, o=(e-E)&63)
__global__ __launch_bounds__(256) void k_edge(
    const float* __restrict__ P1, const float* __restrict__ P2,
    const float* __restrict__ G1, const float* __restrict__ G2,
    const float* __restrict__ b1a, const float* __restrict__ W2a, const float* __restrict__ b2a,
    const float* __restrict__ b1g, const float* __restrict__ W2g, const float* __restrict__ b2g,
    const float* __restrict__ W1f, const float* __restrict__ b1f,
    const float* __restrict__ W2f, const float* __restrict__ b2f,
    float* __restrict__ wE) {
  const int e = blockIdx.x * 256 + threadIdx.x;
  int s, dn;
  if (e < E_NUM) {
    const int t = e >> 6, o = e & 63;
    s = t; dn = T_NUM + ((13 * t + o) & 1023);
  } else {
    const int e2 = e - E_NUM;
    const int t = e2 >> 6, o = e2 & 63;
    s = T_NUM + ((13 * t + o) & 1023); dn = t;
  }
  const float4* p1 = (const float4*)(P1 + (size_t)s * 64);
  const float4* p2 = (const float4*)(P2 + (size_t)dn * 64);
  const float4* b1 = (const float4*)b1a;
  const float4* w2 = (const float4*)W2a;
  float a1 = b2a[0];
#pragma unroll
  for (int i = 0; i < 16; i++) {
    const float4 pa = p1[i], pb = p2[i], bb = b1[i], ww = w2[i];
    a1 += fmaxf(pa.x + pb.x + bb.x, 0.f) * ww.x + fmaxf(pa.y + pb.y + bb.y, 0.f) * ww.y +
          fmaxf(pa.z + pb.z + bb.z, 0.f) * ww.z + fmaxf(pa.w + pb.w + bb.w, 0.f) * ww.w;
  }
  const float4* g1 = (const float4*)(G1 + (size_t)s * 16);
  const float4* g2 = (const float4*)(G2 + (size_t)dn * 16);
  const float4* bg = (const float4*)b1g;
  const float4* wg = (const float4*)W2g;
  float a2 = b2g[0];
#pragma unroll
  for (int i = 0; i < 4; i++) {
    const float4 pa = g1[i], pb = g2[i], bb = bg[i], ww = wg[i];
    a2 += fmaxf(pa.x + pb.x + bb.x, 0.f) * ww.x + fmaxf(pa.y + pb.y + bb.y, 0.f) * ww.y +
          fmaxf(pa.z + pb.z + bb.z, 0.f) * ww.z + fmaxf(pa.w + pb.w + bb.w, 0.f) * ww.w;
  }
  float acc = b2f[0];
#pragma unroll
  for (int jj = 0; jj < 8; jj++) {
    const float h = fmaxf(a1 * W1f[jj] + a2 * W1f[8 + jj] + b1f[jj], 0.f);
    acc = fmaf(h, W2f[jj], acc);
  }
  wE[e] = acc;
}

// ======== fused: msg (analytic adjacency) + out GEMM + row norms ========
__global__ __launch_bounds__(256) void k_msg_out(
    const float* __restrict__ wE, const float* __restrict__ node,
    const float* __restrict__ Wn, const float* __restrict__ Wm,
    const float* __restrict__ bo, float* __restrict__ outE, float* __restrict__ nrm) {
  __shared__ __align__(16) float ms[8][D_EMB];
  __shared__ float wsh[8][64];
  __shared__ int ssh[8][64];
  __shared__ float redn[4][8];
  const int j = threadIdx.x;
  const int lane = j & 63, wid = j >> 6;
  const int row0 = blockIdx.x * 8;
  for (int idx = j; idx < 512; idx += 256) {
    const int r = idx >> 6, o = idx & 63;
    const int n = row0 + r;
    int e, src;
    if (n < T_NUM) {              // tracklet: incoming reversed edges, contiguous
      e = E_NUM + n * 64 + o;
      src = T_NUM + ((13 * n + o) & 1023);
    } else {                      // det d: incoming from tracklet t=709(d-o)
      const int d = n - T_NUM;
      const int t = (709 * (d - o)) & 1023;
      e = t * 64 + o;
      src = t;
    }
    wsh[r][o] = wE[e];
    ssh[r][o] = src;
  }
  __syncthreads();
#pragma unroll 1
  for (int r = 0; r < 8; r++) {
    float acc = 0.f;
    for (int i = 0; i < 64; i++)
      acc = fmaf(wsh[r][i], node[(size_t)ssh[r][i] * D_EMB + j], acc);
    ms[r][j] = acc;
  }
  __syncthreads();
  float acc[8];
  const float bj = bo[j];
#pragma unroll
  for (int r = 0; r < 8; r++) acc[r] = bj;
  const float* nrow = node + (size_t)row0 * D_EMB;
  for (int k = 0; k < D_EMB; k += 4) {
    const float wn0 = Wn[(k + 0) * D_EMB + j], wm0 = Wm[(k + 0) * D_EMB + j];
    const float wn1 = Wn[(k + 1) * D_EMB + j], wm1 = Wm[(k + 1) * D_EMB + j];
    const float wn2 = Wn[(k + 2) * D_EMB + j], wm2 = Wm[(k + 2) * D_EMB + j];
    const float wn3 = Wn[(k + 3) * D_EMB + j], wm3 = Wm[(k + 3) * D_EMB + j];
#pragma unroll
    for (int r = 0; r < 8; r++) {
      const float4 nv = *reinterpret_cast<const float4*>(nrow + (size_t)r * D_EMB + k);
      const float4 mv = *reinterpret_cast<const float4*>(&ms[r][k]);
      acc[r] = fmaf(nv.x, wn0, acc[r]); acc[r] = fmaf(mv.x, wm0, acc[r]);
      acc[r] = fmaf(nv.y, wn1, acc[r]); acc[r] = fmaf(mv.y, wm1, acc[r]);
      acc[r] = fmaf(nv.z, wn2, acc[r]); acc[r] = fmaf(mv.z, wm2, acc[r]);
      acc[r] = fmaf(nv.w, wn3, acc[r]); acc[r] = fmaf(mv.w, wm3, acc[r]);
    }
  }
#pragma unroll
  for (int r = 0; r < 8; r++) {
    acc[r] = fmaxf(acc[r], 0.f);
    outE[(size_t)(row0 + r) * D_EMB + j] = acc[r];
  }
#pragma unroll
  for (int r = 0; r < 8; r++) {
    float sq = acc[r] * acc[r];
#pragma unroll
    for (int o = 32; o > 0; o >>= 1) sq += __shfl_down(sq, o, 64);
    if (lane == 0) redn[wid][r] = sq;
  }
  __syncthreads();
  if (j < 8)
    nrm[row0 + j] = sqrtf(redn[0][j] + redn[1][j] + redn[2][j] + redn[3][j]);
}

// ======== affinity -> banded kernel buffers (permuted row space) ========
// t' = 13*t mod 1024 ; row t' window covers cols [t', t'+63]
// Kbp[t'][  (t'&3) + m        ] = K  (m = (d - t') mod 1024, < 64)
// KTfp[d ][ ((d+961)&3) + 63-m] = K  (col d window covers rows [d-63, d])
__global__ __launch_bounds__(256) void k_aff(
    const float* __restrict__ outE, const float* __restrict__ nrm,
    const float* __restrict__ cov,
    const float* __restrict__ W1c, const float* __restrict__ b1c,
    const float* __restrict__ W2c, const float* __restrict__ b2c,
    float* __restrict__ Kbp, float* __restrict__ KTfp) {
  const int e = blockIdx.x * 256 + threadIdx.x;
  const int t = e >> 6, o = e & 63;
  const int s = t;
  const int d = (13 * t + o) & 1023;
  const int dn = T_NUM + d;
  const float4* oa = (const float4*)(outE + (size_t)s * D_EMB);
  const float4* ob = (const float4*)(outE + (size_t)dn * D_EMB);
  float dot = 0.f;
#pragma unroll 8
  for (int i = 0; i < 64; i++) {
    const float4 a = oa[i], bq = ob[i];
    dot += a.x * bq.x + a.y * bq.y + a.z * bq.z + a.w * bq.w;
  }
  const float cosv = dot / fmaxf(nrm[s] * nrm[dn], 1e-6f);
  const float4 A = ((const float4*)cov)[s];
  const float4 B = ((const float4*)cov)[dn];
  const float ltx = fmaxf(A.x, B.x), lty = fmaxf(A.y, B.y);
  const float rbx = fminf(A.z, B.z), rby = fminf(A.w, B.w);
  const float wx = fmaxf(rbx - ltx, 0.f), wy = fmaxf(rby - lty, 0.f);
  const float inter = wx * wy;
  const float areaA = (A.z - A.x) * (A.w - A.y);
  const float areaB = (B.z - B.x) * (B.w - B.y);
  const float iou = inter / (areaA + areaB - inter + 1e-9f);
  float aff = b2c[0];
#pragma unroll
  for (int jj = 0; jj < 8; jj++) {
    const float h = fmaxf(cosv * W1c[jj] + iou * W1c[8 + jj] + b1c[jj], 0.f);
    aff = fmaf(h, W2c[jj], aff);
  }
  const float Kv = __expf(aff * 5.0f);
  const int tp = (13 * s) & 1023;
  const int m = (d - tp) & 1023;            // == o
  Kbp[tp * 68 + (tp & 3) + m] = Kv;
  const int s0 = (d + 961) & 1023;          // col-window start (d-63 mod 1024)
  KTfp[d * 68 + (s0 & 3) + 63 - m] = Kv;
}

// ======== Sinkhorn: bf16 K bands in registers, 512 thr (2 rows+2 cols) =====
__device__ __forceinline__ unsigned bf16r(float x) {
  const unsigned u = __float_as_uint(x);
  return (u + 0x7fffu + ((u >> 16) & 1u)) >> 16;  // RNE
}
__device__ __forceinline__ float bflo(unsigned p) { return __uint_as_float(p << 16); }
__device__ __forceinline__ float bfhi(unsigned p) { return __uint_as_float(p & 0xffff0000u); }

__global__ __launch_bounds__(512, 2) void k_sinkhorn(
    const float* __restrict__ Kbp, const float* __restrict__ KTfp,
    float* __restrict__ ug, float* __restrict__ vg) {
  __shared__ __align__(16) float u_lds[1092];   // replicated: [1024+i]=[i], i<68
  __shared__ __align__(16) float v_lds[1092];
  __shared__ float red_u[8];
  __shared__ float red_v[8];
  const int tid = threadIdx.x;
  const int lane = tid & 63, wid = tid >> 6;
  const int r0 = tid, r1 = tid + 512;
  unsigned kb0[34], kb1[34], kc0[34], kc1[34];
  {
    const float4* a = (const float4*)(Kbp + (size_t)r0 * 68);
    const float4* bq = (const float4*)(Kbp + (size_t)r1 * 68);
    const float4* c = (const float4*)(KTfp + (size_t)r0 * 68);
    const float4* dq = (const float4*)(KTfp + (size_t)r1 * 68);
#pragma unroll
    for (int i = 0; i < 17; i++) {
      float4 f = a[i];  kb0[2*i] = bf16r(f.x) | (bf16r(f.y) << 16); kb0[2*i+1] = bf16r(f.z) | (bf16r(f.w) << 16);
      f = bq[i];        kb1[2*i] = bf16r(f.x) | (bf16r(f.y) << 16); kb1[2*i+1] = bf16r(f.z) | (bf16r(f.w) << 16);
      f = c[i];         kc0[2*i] = bf16r(f.x) | (bf16r(f.y) << 16); kc0[2*i+1] = bf16r(f.z) | (bf16r(f.w) << 16);
      f = dq[i];        kc1[2*i] = bf16r(f.x) | (bf16r(f.y) << 16); kc1[2*i+1] = bf16r(f.z) | (bf16r(f.w) << 16);
    }
  }
  float u0 = 1.f, u1 = 1.f, v0 = 1.f, v1 = 1.f, u_sl = 1.f, v_sl = 1.f;
  v_lds[r0] = 1.f; v_lds[r1] = 1.f;
  if (tid < 68) v_lds[1024 + tid] = 1.f;
  if (tid < 8) red_v[tid] = 128.f;
  const float slack = 0.36787944117144233f;  // exp(SLACK*LAM) = exp(-1)
  const int qa0 = r0 >> 2, qa1 = r1 >> 2;
  const int qc0 = ((r0 + 961) & 1023) >> 2;
  const int qc1 = ((r1 + 961) & 1023) >> 2;
  __syncthreads();
#pragma unroll 1
  for (int it = 0; it < 8; ++it) {
    // ---- row phase: s_i = K_i . v_window + slack*v_slack
    float s00 = 0.f, s01 = 0.f, s10 = 0.f, s11 = 0.f;
    const float4* vq = (const float4*)v_lds;
#pragma unroll
    for (int c = 0; c < 17; c++) {
      const float4 va = vq[qa0 + c];
      unsigned p0 = kb0[2*c], p1 = kb0[2*c+1];
      s00 = fmaf(bflo(p0), va.x, s00); s00 = fmaf(bfhi(p0), va.y, s00);
      s01 = fmaf(bflo(p1), va.z, s01); s01 = fmaf(bfhi(p1), va.w, s01);
      const float4 vb = vq[qa1 + c];
      p0 = kb1[2*c]; p1 = kb1[2*c+1];
      s10 = fmaf(bflo(p0), vb.x, s10); s10 = fmaf(bfhi(p0), vb.y, s10);
      s11 = fmaf(bflo(p1), vb.z, s11); s11 = fmaf(bfhi(p1), vb.w, s11);
    }
    float sumv = red_v[0] + red_v[1] + red_v[2] + red_v[3] +
                 red_v[4] + red_v[5] + red_v[6] + red_v[7];
    const float sA = s00 + s01 + slack * v_sl;
    const float sB = s10 + s11 + slack * v_sl;
    const float u0n = u0 / (u0 * sA + 1e-9f);
    const float u1n = u1 / (u1 * sB + 1e-9f);
    u_sl = u_sl / (u_sl * slack * (sumv + v_sl) + 1e-9f);
    u0 = u0n; u1 = u1n;
    u_lds[r0] = u0; u_lds[r1] = u1;
    if (tid < 68) u_lds[1024 + tid] = u0;
    float r = u0 + u1;
#pragma unroll
    for (int o = 32; o > 0; o >>= 1) r += __shfl_down(r, o, 64);
    if (lane == 0) red_u[wid] = r;
    __syncthreads();
    // ---- col phase: t_j = KT_j . u_window + slack*u_slack
    float t00 = 0.f, t01 = 0.f, t10 = 0.f, t11 = 0.f;
    const float4* uq = (const float4*)u_lds;
#pragma unroll
    for (int c = 0; c < 17; c++) {
      const float4 ua = uq[qc0 + c];
      unsigned p0 = kc0[2*c], p1 = kc0[2*c+1];
      t00 = fmaf(bflo(p0), ua.x, t00); t00 = fmaf(bfhi(p0), ua.y, t00);
      t01 = fmaf(bflo(p1), ua.z, t01); t01 = fmaf(bfhi(p1), ua.w, t01);
      const float4 ub = uq[qc1 + c];
      p0 = kc1[2*c]; p1 = kc1[2*c+1];
      t10 = fmaf(bflo(p0), ub.x, t10); t10 = fmaf(bfhi(p0), ub.y, t10);
      t11 = fmaf(bflo(p1), ub.z, t11); t11 = fmaf(bfhi(p1), ub.w, t11);
    }
    float sumu = red_u[0] + red_u[1] + red_u[2] + red_u[3] +
                 red_u[4] + red_u[5] + red_u[6] + red_u[7];
    const float tA = t00 + t01 + slack * u_sl;
    const float tB = t10 + t11 + slack * u_sl;
    const float v0n = v0 / (v0 * tA + 1e-9f);
    const float v1n = v1 / (v1 * tB + 1e-9f);
    v_sl = v_sl / (v_sl * slack * (sumu + u_sl) + 1e-9f);
    v0 = v0n; v1 = v1n;
    v_lds[r0] = v0; v_lds[r1] = v1;
    if (tid < 68) v_lds[1024 + tid] = v0;
    float rr = v0 + v1;
#pragma unroll
    for (int o = 32; o > 0; o >>= 1) rr += __shfl_down(rr, o, 64);
    if (lane == 0) red_v[wid] = rr;
    __syncthreads();
  }
  ug[r0] = u0; ug[r1] = u1;   // indexed by t' (permuted row space)
  vg[r0] = v0; vg[r1] = v1;   // indexed by d
}

// ======== dense final write: out[t][d] = u[t']*K*v[d] (0 off-band) ========
__global__ __launch_bounds__(256) void k_final(
    const float* __restrict__ Kbp, const float* __restrict__ ug,
    const float* __restrict__ vg, float* __restrict__ out) {
  const int t = blockIdx.x;
  const int tp = (13 * t) & 1023;
  const float u = ug[tp];
  const float* krow = Kbp + (size_t)tp * 68 + (tp & 3);
  const int d0 = threadIdx.x * 4;
  const float4 v4 = ((const float4*)vg)[threadIdx.x];
  float4 o4;
  const int m0 = (d0 - tp) & 1023;
  const int m1 = (d0 + 1 - tp) & 1023;
  const int m2 = (d0 + 2 - tp) & 1023;
  const int m3 = (d0 + 3 - tp) & 1023;
  o4.x = (m0 < 64) ? u * krow[m0] * v4.x : 0.f;
  o4.y = (m1 < 64) ? u * krow[m1] * v4.y : 0.f;
  o4.z = (m2 < 64) ? u * krow[m2] * v4.z : 0.f;
  o4.w = (m3 < 64) ? u * krow[m3] * v4.w : 0.f;
  ((float4*)out)[(size_t)t * 256 + threadIdx.x] = o4;
  if (t == 0 && threadIdx.x == 0) {
    out[(size_t)2 * T_NUM * DET_NUM] = 1024.0f;      // det_num
    out[(size_t)2 * T_NUM * DET_NUM + 1] = 1024.0f;  // tracklet_num
  }
}

extern "C" void kernel_launch(void* const* d_in, const int* in_sizes, int n_in,
                              void* d_out, int out_size, void* d_ws, size_t ws_size,
                              hipStream_t stream) {
  const float* x      = (const float*)d_in[0];
  const float* coords = (const float*)d_in[1];
  const float* cov    = (const float*)d_in[2];
  const float* gt     = (const float*)d_in[3];
  const float* W_enc  = (const float*)d_in[5];
  const float* b_enc  = (const float*)d_in[6];
  const float* W1a    = (const float*)d_in[7];
  const float* b1a    = (const float*)d_in[8];
  const float* W2a    = (const float*)d_in[9];
  const float* b2a    = (const float*)d_in[10];
  const float* W1g    = (const float*)d_in[11];
  const float* b1g    = (const float*)d_in[12];
  const float* W2g    = (const float*)d_in[13];
  const float* b2g    = (const float*)d_in[14];
  const float* W1f    = (const float*)d_in[15];
  const float* b1f    = (const float*)d_in[16];
  const float* W2f    = (const float*)d_in[17];
  const float* b2f    = (const float*)d_in[18];
  const float* Wn     = (const float*)d_in[19];
  const float* Wm     = (const float*)d_in[20];
  const float* bo     = (const float*)d_in[21];
  const float* W1c    = (const float*)d_in[22];
  const float* b1c    = (const float*)d_in[23];
  const float* W2c    = (const float*)d_in[24];
  const float* b2c    = (const float*)d_in[25];

  char* ws = (char*)d_ws;
  size_t off = 0;
  auto alloc = [&](size_t bytes) {
    char* p = ws + off;
    off = (off + bytes + 255) & ~(size_t)255;
    return p;
  };
  float* node  = (float*)alloc((size_t)N_NODES * D_EMB * 4);
  float* P1    = (float*)alloc((size_t)N_NODES * 64 * 4);
  float* P2    = (float*)alloc((size_t)N_NODES * 64 * 4);
  float* G1    = (float*)alloc((size_t)N_NODES * 16 * 4);
  float* G2    = (float*)alloc((size_t)N_NODES * 16 * 4);
  float* wE    = (float*)alloc((size_t)TWO_E * 4);
  float* outE  = (float*)alloc((size_t)N_NODES * D_EMB * 4);
  float* nrm   = (float*)alloc((size_t)N_NODES * 4);
  float* Kbp   = (float*)alloc((size_t)1024 * 68 * 4);
  float* KTfp  = (float*)alloc((size_t)1024 * 68 * 4);   // contiguous w/ Kbp
  float* ug    = (float*)alloc(1024 * 4);
  float* vg    = (float*)alloc(1024 * 4);
  float* out   = (float*)d_out;

  hipMemsetAsync(Kbp, 0, (size_t)2 * 1024 * 68 * 4, stream);  // band pads
  hipMemcpyAsync(out + (size_t)T_NUM * DET_NUM, gt, (size_t)T_NUM * DET_NUM * 4,
                 hipMemcpyDeviceToDevice, stream);

  k_enc_pg<<<N_NODES / 8, 256, 0, stream>>>(x, W_enc, b_enc, coords, W1a, W1g,
                                            node, P1, P2, G1, G2);
  k_edge<<<TWO_E / 256, 256, 0, stream>>>(P1, P2, G1, G2, b1a, W2a, b2a,
                                          b1g, W2g, b2g, W1f, b1f, W2f, b2f, wE);
  k_msg_out<<<N_NODES / 8, 256, 0, stream>>>(wE, node, Wn, Wm, bo, outE, nrm);
  k_aff<<<E_NUM / 256, 256, 0, stream>>>(outE, nrm, cov, W1c, b1c, W2c, b2c,
                                         Kbp, KTfp);
  k_sinkhorn<<<1, 512, 0, stream>>>(Kbp, KTfp, ug, vg);
  k_final<<<T_NUM, 256, 0, stream>>>(Kbp, ug, vg, out);
}

// Round 4
// 297.749 us; speedup vs baseline: 1.5093x; 1.1241x over previous
//
#include <hip/hip_runtime.h>

#define T_NUM 1024
#define DET_NUM 1024
#define E_NUM 65536
#define TWO_E 131072
#define N_NODES 2048
#define D_IN 512
#define D_EMB 256

// ======== fused encoder + P1/P2/G1/G2 precompute (4 rows/block) ========
__global__ __launch_bounds__(256) void k_enc_pg(
    const float* __restrict__ x, const float* __restrict__ W,
    const float* __restrict__ b, const float* __restrict__ coords,
    const float* __restrict__ W1a, const float* __restrict__ W1g,
    float* __restrict__ node, float* __restrict__ P1, float* __restrict__ P2,
    float* __restrict__ G1, float* __restrict__ G2) {
  __shared__ __align__(16) float ns[4][D_EMB];
  const int j = threadIdx.x;
  const int row0 = blockIdx.x * 4;
  float acc[4];
  const float bj = b[j];
#pragma unroll
  for (int r = 0; r < 4; r++) acc[r] = bj;
  const float* xr = x + (size_t)row0 * D_IN;
  for (int k = 0; k < D_IN; k += 4) {
    const float w0 = W[(k + 0) * D_EMB + j];
    const float w1 = W[(k + 1) * D_EMB + j];
    const float w2 = W[(k + 2) * D_EMB + j];
    const float w3 = W[(k + 3) * D_EMB + j];
#pragma unroll
    for (int r = 0; r < 4; r++) {
      const float4 xv = *reinterpret_cast<const float4*>(xr + (size_t)r * D_IN + k);
      acc[r] = fmaf(xv.x, w0, acc[r]);
      acc[r] = fmaf(xv.y, w1, acc[r]);
      acc[r] = fmaf(xv.z, w2, acc[r]);
      acc[r] = fmaf(xv.w, w3, acc[r]);
    }
  }
#pragma unroll
  for (int r = 0; r < 4; r++) {
    const float v = fmaxf(acc[r], 0.f);
    node[(size_t)(row0 + r) * D_EMB + j] = v;
    ns[r][j] = v;
  }
  __syncthreads();
  {
    const int r = j >> 6, h = j & 63;   // 4 rows x 64 h = 256 threads
    float a1 = 0.f, a2 = 0.f;
    for (int k = 0; k < D_EMB; k += 4) {
      const float4 nv = *reinterpret_cast<const float4*>(&ns[r][k]);
      a1 = fmaf(nv.x, W1a[(k + 0) * 64 + h], a1);
      a1 = fmaf(nv.y, W1a[(k + 1) * 64 + h], a1);
      a1 = fmaf(nv.z, W1a[(k + 2) * 64 + h], a1);
      a1 = fmaf(nv.w, W1a[(k + 3) * 64 + h], a1);
      a2 = fmaf(nv.x, W1a[(D_EMB + k + 0) * 64 + h], a2);
      a2 = fmaf(nv.y, W1a[(D_EMB + k + 1) * 64 + h], a2);
      a2 = fmaf(nv.z, W1a[(D_EMB + k + 2) * 64 + h], a2);
      a2 = fmaf(nv.w, W1a[(D_EMB + k + 3) * 64 + h], a2);
    }
    P1[(size_t)(row0 + r) * 64 + h] = a1;
    P2[(size_t)(row0 + r) * 64 + h] = a2;
  }
  if (j < 64) {
    const int r = j >> 4, h = j & 15;
    const int n = row0 + r;
    float g1 = 0.f, g2 = 0.f;
#pragma unroll
    for (int k = 0; k < 4; k++) {
      const float c = coords[(size_t)n * 4 + k];
      g1 = fmaf(c, W1g[k * 16 + h], g1);
      g2 = fmaf(c, W1g[(4 + k) * 16 + h], g2);
    }
    G1[(size_t)n * 16 + h] = g1;
    G2[(size_t)n * 16 + h] = g2;
  }
}

// ======== per-edge scalar weight (analytic edge structure) ========
__global__ __launch_bounds__(256) void k_edge(
    const float* __restrict__ P1, const float* __restrict__ P2,
    const float* __restrict__ G1, const float* __restrict__ G2,
    const float* __restrict__ b1a, const float* __restrict__ W2a, const float* __restrict__ b2a,
    const float* __restrict__ b1g, const float* __restrict__ W2g, const float* __restrict__ b2g,
    const float* __restrict__ W1f, const float* __restrict__ b1f,
    const float* __restrict__ W2f, const float* __restrict__ b2f,
    float* __restrict__ wE) {
  const int e = blockIdx.x * 256 + threadIdx.x;
  int s, dn;
  if (e < E_NUM) {
    const int t = e >> 6, o = e & 63;
    s = t; dn = T_NUM + ((13 * t + o) & 1023);
  } else {
    const int e2 = e - E_NUM;
    const int t = e2 >> 6, o = e2 & 63;
    s = T_NUM + ((13 * t + o) & 1023); dn = t;
  }
  const float4* p1 = (const float4*)(P1 + (size_t)s * 64);
  const float4* p2 = (const float4*)(P2 + (size_t)dn * 64);
  const float4* b1 = (const float4*)b1a;
  const float4* w2 = (const float4*)W2a;
  float a1 = b2a[0];
#pragma unroll
  for (int i = 0; i < 16; i++) {
    const float4 pa = p1[i], pb = p2[i], bb = b1[i], ww = w2[i];
    a1 += fmaxf(pa.x + pb.x + bb.x, 0.f) * ww.x + fmaxf(pa.y + pb.y + bb.y, 0.f) * ww.y +
          fmaxf(pa.z + pb.z + bb.z, 0.f) * ww.z + fmaxf(pa.w + pb.w + bb.w, 0.f) * ww.w;
  }
  const float4* g1 = (const float4*)(G1 + (size_t)s * 16);
  const float4* g2 = (const float4*)(G2 + (size_t)dn * 16);
  const float4* bg = (const float4*)b1g;
  const float4* wg = (const float4*)W2g;
  float a2 = b2g[0];
#pragma unroll
  for (int i = 0; i < 4; i++) {
    const float4 pa = g1[i], pb = g2[i], bb = bg[i], ww = wg[i];
    a2 += fmaxf(pa.x + pb.x + bb.x, 0.f) * ww.x + fmaxf(pa.y + pb.y + bb.y, 0.f) * ww.y +
          fmaxf(pa.z + pb.z + bb.z, 0.f) * ww.z + fmaxf(pa.w + pb.w + bb.w, 0.f) * ww.w;
  }
  float acc = b2f[0];
#pragma unroll
  for (int jj = 0; jj < 8; jj++) {
    const float h = fmaxf(a1 * W1f[jj] + a2 * W1f[8 + jj] + b1f[jj], 0.f);
    acc = fmaf(h, W2f[jj], acc);
  }
  wE[e] = acc;
}

// ======== fused: msg (analytic adjacency) + out GEMM + row norms (4 rows) ==
__global__ __launch_bounds__(256) void k_msg_out(
    const float* __restrict__ wE, const float* __restrict__ node,
    const float* __restrict__ Wn, const float* __restrict__ Wm,
    const float* __restrict__ bo, float* __restrict__ outE, float* __restrict__ nrm) {
  __shared__ __align__(16) float ms[4][D_EMB];
  __shared__ float wsh[4][64];
  __shared__ int ssh[4][64];
  __shared__ float redn[4][4];
  const int j = threadIdx.x;
  const int lane = j & 63, wid = j >> 6;
  const int row0 = blockIdx.x * 4;
  {
    const int r = j >> 6, o = j & 63;   // 256 threads = 4 rows x 64 edges
    const int n = row0 + r;
    int e, src;
    if (n < T_NUM) {              // tracklet: incoming reversed edges, contiguous
      e = E_NUM + n * 64 + o;
      src = T_NUM + ((13 * n + o) & 1023);
    } else {                      // det d: incoming from tracklet t=709(d-o)
      const int d = n - T_NUM;
      const int t = (709 * (d - o)) & 1023;
      e = t * 64 + o;
      src = t;
    }
    wsh[r][o] = wE[e];
    ssh[r][o] = src;
  }
  __syncthreads();
#pragma unroll 1
  for (int r = 0; r < 4; r++) {
    float acc = 0.f;
    for (int i = 0; i < 64; i++)
      acc = fmaf(wsh[r][i], node[(size_t)ssh[r][i] * D_EMB + j], acc);
    ms[r][j] = acc;
  }
  __syncthreads();
  float acc[4];
  const float bj = bo[j];
#pragma unroll
  for (int r = 0; r < 4; r++) acc[r] = bj;
  const float* nrow = node + (size_t)row0 * D_EMB;
  for (int k = 0; k < D_EMB; k += 4) {
    const float wn0 = Wn[(k + 0) * D_EMB + j], wm0 = Wm[(k + 0) * D_EMB + j];
    const float wn1 = Wn[(k + 1) * D_EMB + j], wm1 = Wm[(k + 1) * D_EMB + j];
    const float wn2 = Wn[(k + 2) * D_EMB + j], wm2 = Wm[(k + 2) * D_EMB + j];
    const float wn3 = Wn[(k + 3) * D_EMB + j], wm3 = Wm[(k + 3) * D_EMB + j];
#pragma unroll
    for (int r = 0; r < 4; r++) {
      const float4 nv = *reinterpret_cast<const float4*>(nrow + (size_t)r * D_EMB + k);
      const float4 mv = *reinterpret_cast<const float4*>(&ms[r][k]);
      acc[r] = fmaf(nv.x, wn0, acc[r]); acc[r] = fmaf(mv.x, wm0, acc[r]);
      acc[r] = fmaf(nv.y, wn1, acc[r]); acc[r] = fmaf(mv.y, wm1, acc[r]);
      acc[r] = fmaf(nv.z, wn2, acc[r]); acc[r] = fmaf(mv.z, wm2, acc[r]);
      acc[r] = fmaf(nv.w, wn3, acc[r]); acc[r] = fmaf(mv.w, wm3, acc[r]);
    }
  }
#pragma unroll
  for (int r = 0; r < 4; r++) {
    acc[r] = fmaxf(acc[r], 0.f);
    outE[(size_t)(row0 + r) * D_EMB + j] = acc[r];
  }
#pragma unroll
  for (int r = 0; r < 4; r++) {
    float sq = acc[r] * acc[r];
#pragma unroll
    for (int o = 32; o > 0; o >>= 1) sq += __shfl_down(sq, o, 64);
    if (lane == 0) redn[wid][r] = sq;
  }
  __syncthreads();
  if (j < 4)
    nrm[row0 + j] = sqrtf(redn[0][j] + redn[1][j] + redn[2][j] + redn[3][j]);
}

// ======== affinity -> banded kernel buffers (permuted row space) ========
__global__ __launch_bounds__(256) void k_aff(
    const float* __restrict__ outE, const float* __restrict__ nrm,
    const float* __restrict__ cov,
    const float* __restrict__ W1c, const float* __restrict__ b1c,
    const float* __restrict__ W2c, const float* __restrict__ b2c,
    float* __restrict__ Kbp, float* __restrict__ KTfp) {
  const int e = blockIdx.x * 256 + threadIdx.x;
  const int t = e >> 6, o = e & 63;
  const int s = t;
  const int d = (13 * t + o) & 1023;
  const int dn = T_NUM + d;
  const float4* oa = (const float4*)(outE + (size_t)s * D_EMB);
  const float4* ob = (const float4*)(outE + (size_t)dn * D_EMB);
  float dot = 0.f;
#pragma unroll 8
  for (int i = 0; i < 64; i++) {
    const float4 a = oa[i], bq = ob[i];
    dot += a.x * bq.x + a.y * bq.y + a.z * bq.z + a.w * bq.w;
  }
  const float cosv = dot / fmaxf(nrm[s] * nrm[dn], 1e-6f);
  const float4 A = ((const float4*)cov)[s];
  const float4 B = ((const float4*)cov)[dn];
  const float ltx = fmaxf(A.x, B.x), lty = fmaxf(A.y, B.y);
  const float rbx = fminf(A.z, B.z), rby = fminf(A.w, B.w);
  const float wx = fmaxf(rbx - ltx, 0.f), wy = fmaxf(rby - lty, 0.f);
  const float inter = wx * wy;
  const float areaA = (A.z - A.x) * (A.w - A.y);
  const float areaB = (B.z - B.x) * (B.w - B.y);
  const float iou = inter / (areaA + areaB - inter + 1e-9f);
  float aff = b2c[0];
#pragma unroll
  for (int jj = 0; jj < 8; jj++) {
    const float h = fmaxf(cosv * W1c[jj] + iou * W1c[8 + jj] + b1c[jj], 0.f);
    aff = fmaf(h, W2c[jj], aff);
  }
  const float Kv = __expf(aff * 5.0f);
  const int tp = (13 * s) & 1023;
  const int m = (d - tp) & 1023;            // == o
  Kbp[tp * 68 + (tp & 3) + m] = Kv;
  const int s0 = (d + 961) & 1023;          // col-window start (d-63 mod 1024)
  KTfp[d * 68 + (s0 & 3) + 63 - m] = Kv;
}

// ======== Sinkhorn: bf16 K bands in registers, 1024 thr, pinned occupancy ==
// amdgpu_waves_per_eu(4,4): exactly 4 waves/SIMD -> 128-VGPR cap and NO
// incentive for the allocator to spill down to 64 for higher occupancy.
__device__ __forceinline__ unsigned bf16r(float x) {
  const unsigned u = __float_as_uint(x);
  return (u + 0x7fffu + ((u >> 16) & 1u)) >> 16;  // RNE
}
__device__ __forceinline__ float bflo(unsigned p) { return __uint_as_float(p << 16); }
__device__ __forceinline__ float bfhi(unsigned p) { return __uint_as_float(p & 0xffff0000u); }

__attribute__((amdgpu_flat_work_group_size(1024, 1024), amdgpu_waves_per_eu(4, 4)))
__global__ void k_sinkhorn(
    const float* __restrict__ Kbp, const float* __restrict__ KTfp,
    float* __restrict__ ug, float* __restrict__ vg) {
  __shared__ __align__(16) float u_lds[1092];   // replicated: [1024+i]=[i], i<68
  __shared__ __align__(16) float v_lds[1092];
  __shared__ float red_u[16];
  __shared__ float red_v[16];
  const int tid = threadIdx.x;
  const int lane = tid & 63, wid = tid >> 6;
  unsigned kb[34], kc[34];
  {
    const float4* s1 = (const float4*)(Kbp + (size_t)tid * 68);
    const float4* s2 = (const float4*)(KTfp + (size_t)tid * 68);
#pragma unroll
    for (int c = 0; c < 17; c++) {
      float4 f = s1[c];
      kb[2 * c] = bf16r(f.x) | (bf16r(f.y) << 16);
      kb[2 * c + 1] = bf16r(f.z) | (bf16r(f.w) << 16);
      f = s2[c];
      kc[2 * c] = bf16r(f.x) | (bf16r(f.y) << 16);
      kc[2 * c + 1] = bf16r(f.z) | (bf16r(f.w) << 16);
    }
  }
  float u_own = 1.f, v_own = 1.f, u_sl = 1.f, v_sl = 1.f;
  v_lds[tid] = 1.f;
  if (tid < 68) v_lds[1024 + tid] = 1.f;
  if (tid < 16) red_v[tid] = 64.f;
  const float slack = 0.36787944117144233f;  // exp(SLACK*LAM) = exp(-1)
  const int qa = tid >> 2;
  const int qc = ((tid + 961) & 1023) >> 2;
  __syncthreads();
#pragma unroll 1
  for (int it = 0; it < 8; ++it) {
    // ---- row phase: s_i = K_i . v_window + slack*v_slack
    float s0 = 0.f, s1a = 0.f;
    const float4* vq = (const float4*)v_lds;
#pragma unroll
    for (int c = 0; c < 17; c++) {
      const float4 v4 = vq[qa + c];
      const unsigned p0 = kb[2 * c], p1 = kb[2 * c + 1];
      s0 = fmaf(bflo(p0), v4.x, s0);
      s0 = fmaf(bfhi(p0), v4.y, s0);
      s1a = fmaf(bflo(p1), v4.z, s1a);
      s1a = fmaf(bfhi(p1), v4.w, s1a);
    }
    float sumv = 0.f;
#pragma unroll
    for (int i = 0; i < 16; i++) sumv += red_v[i];
    const float s = s0 + s1a + slack * v_sl;
    const float unew = u_own / (u_own * s + 1e-9f);
    u_sl = u_sl / (u_sl * slack * (sumv + v_sl) + 1e-9f);
    u_own = unew;
    u_lds[tid] = unew;
    if (tid < 68) u_lds[1024 + tid] = unew;
    float r = unew;
#pragma unroll
    for (int o = 32; o > 0; o >>= 1) r += __shfl_down(r, o, 64);
    if (lane == 0) red_u[wid] = r;
    __syncthreads();
    // ---- col phase: t_j = KT_j . u_window + slack*u_slack
    float t0 = 0.f, t1a = 0.f;
    const float4* uq = (const float4*)u_lds;
#pragma unroll
    for (int c = 0; c < 17; c++) {
      const float4 u4 = uq[qc + c];
      const unsigned p0 = kc[2 * c], p1 = kc[2 * c + 1];
      t0 = fmaf(bflo(p0), u4.x, t0);
      t0 = fmaf(bfhi(p0), u4.y, t0);
      t1a = fmaf(bflo(p1), u4.z, t1a);
      t1a = fmaf(bfhi(p1), u4.w, t1a);
    }
    float sumu = 0.f;
#pragma unroll
    for (int i = 0; i < 16; i++) sumu += red_u[i];
    const float t = t0 + t1a + slack * u_sl;
    const float vnew = v_own / (v_own * t + 1e-9f);
    v_sl = v_sl / (v_sl * slack * (sumu + u_sl) + 1e-9f);
    v_own = vnew;
    v_lds[tid] = vnew;
    if (tid < 68) v_lds[1024 + tid] = vnew;
    float rr = vnew;
#pragma unroll
    for (int o = 32; o > 0; o >>= 1) rr += __shfl_down(rr, o, 64);
    if (lane == 0) red_v[wid] = rr;
    __syncthreads();
  }
  ug[tid] = u_own;   // indexed by t' (permuted row space)
  vg[tid] = v_own;   // indexed by d
}

// ======== dense final write: out[t][d] = u[t']*K*v[d] (0 off-band) ========
__global__ __launch_bounds__(256) void k_final(
    const float* __restrict__ Kbp, const float* __restrict__ ug,
    const float* __restrict__ vg, float* __restrict__ out) {
  const int t = blockIdx.x;
  const int tp = (13 * t) & 1023;
  const float u = ug[tp];
  const float* krow = Kbp + (size_t)tp * 68 + (tp & 3);
  const int d0 = threadIdx.x * 4;
  const float4 v4 = ((const float4*)vg)[threadIdx.x];
  float4 o4;
  const int m0 = (d0 - tp) & 1023;
  const int m1 = (d0 + 1 - tp) & 1023;
  const int m2 = (d0 + 2 - tp) & 1023;
  const int m3 = (d0 + 3 - tp) & 1023;
  o4.x = (m0 < 64) ? u * krow[m0] * v4.x : 0.f;
  o4.y = (m1 < 64) ? u * krow[m1] * v4.y : 0.f;
  o4.z = (m2 < 64) ? u * krow[m2] * v4.z : 0.f;
  o4.w = (m3 < 64) ? u * krow[m3] * v4.w : 0.f;
  ((float4*)out)[(size_t)t * 256 + threadIdx.x] = o4;
  if (t == 0 && threadIdx.x == 0) {
    out[(size_t)2 * T_NUM * DET_NUM] = 1024.0f;      // det_num
    out[(size_t)2 * T_NUM * DET_NUM + 1] = 1024.0f;  // tracklet_num
  }
}

extern "C" void kernel_launch(void* const* d_in, const int* in_sizes, int n_in,
                              void* d_out, int out_size, void* d_ws, size_t ws_size,
                              hipStream_t stream) {
  const float* x      = (const float*)d_in[0];
  const float* coords = (const float*)d_in[1];
  const float* cov    = (const float*)d_in[2];
  const float* gt     = (const float*)d_in[3];
  const float* W_enc  = (const float*)d_in[5];
  const float* b_enc  = (const float*)d_in[6];
  const float* W1a    = (const float*)d_in[7];
  const float* b1a    = (const float*)d_in[8];
  const float* W2a    = (const float*)d_in[9];
  const float* b2a    = (const float*)d_in[10];
  const float* W1g    = (const float*)d_in[11];
  const float* b1g    = (const float*)d_in[12];
  const float* W2g    = (const float*)d_in[13];
  const float* b2g    = (const float*)d_in[14];
  const float* W1f    = (const float*)d_in[15];
  const float* b1f    = (const float*)d_in[16];
  const float* W2f    = (const float*)d_in[17];
  const float* b2f    = (const float*)d_in[18];
  const float* Wn     = (const float*)d_in[19];
  const float* Wm     = (const float*)d_in[20];
  const float* bo     = (const float*)d_in[21];
  const float* W1c    = (const float*)d_in[22];
  const float* b1c    = (const float*)d_in[23];
  const float* W2c    = (const float*)d_in[24];
  const float* b2c    = (const float*)d_in[25];

  char* ws = (char*)d_ws;
  size_t off = 0;
  auto alloc = [&](size_t bytes) {
    char* p = ws + off;
    off = (off + bytes + 255) & ~(size_t)255;
    return p;
  };
  float* node  = (float*)alloc((size_t)N_NODES * D_EMB * 4);
  float* P1    = (float*)alloc((size_t)N_NODES * 64 * 4);
  float* P2    = (float*)alloc((size_t)N_NODES * 64 * 4);
  float* G1    = (float*)alloc((size_t)N_NODES * 16 * 4);
  float* G2    = (float*)alloc((size_t)N_NODES * 16 * 4);
  float* wE    = (float*)alloc((size_t)TWO_E * 4);
  float* outE  = (float*)alloc((size_t)N_NODES * D_EMB * 4);
  float* nrm   = (float*)alloc((size_t)N_NODES * 4);
  float* Kbp   = (float*)alloc((size_t)1024 * 68 * 4);
  float* KTfp  = (float*)alloc((size_t)1024 * 68 * 4);   // contiguous w/ Kbp
  float* ug    = (float*)alloc(1024 * 4);
  float* vg    = (float*)alloc(1024 * 4);
  float* out   = (float*)d_out;

  hipMemsetAsync(Kbp, 0, (size_t)2 * 1024 * 68 * 4, stream);  // band pads
  hipMemcpyAsync(out + (size_t)T_NUM * DET_NUM, gt, (size_t)T_NUM * DET_NUM * 4,
                 hipMemcpyDeviceToDevice, stream);

  k_enc_pg<<<N_NODES / 4, 256, 0, stream>>>(x, W_enc, b_enc, coords, W1a, W1g,
                                            node, P1, P2, G1, G2);
  k_edge<<<TWO_E / 256, 256, 0, stream>>>(P1, P2, G1, G2, b1a, W2a, b2a,
                                          b1g, W2g, b2g, W1f, b1f, W2f, b2f, wE);
  k_msg_out<<<N_NODES / 4, 256, 0, stream>>>(wE, node, Wn, Wm, bo, outE, nrm);
  k_aff<<<E_NUM / 256, 256, 0, stream>>>(outE, nrm, cov, W1c, b1c, W2c, b2c,
                                         Kbp, KTfp);
  k_sinkhorn<<<1, 1024, 0, stream>>>(Kbp, KTfp, ug, vg);
  k_final<<<T_NUM, 256, 0, stream>>>(Kbp, ug, vg, out);
}

// Round 5
// 290.056 us; speedup vs baseline: 1.5493x; 1.0265x over previous
//
#include <hip/hip_runtime.h>

#define T_NUM 1024
#define DET_NUM 1024
#define E_NUM 65536
#define TWO_E 131072
#define N_NODES 2048
#define D_IN 512
#define D_EMB 256

// ======== fused encoder + P1/P2/G1/G2 precompute (4 rows/block) ========
__global__ __launch_bounds__(256) void k_enc_pg(
    const float* __restrict__ x, const float* __restrict__ W,
    const float* __restrict__ b, const float* __restrict__ coords,
    const float* __restrict__ W1a, const float* __restrict__ W1g,
    float* __restrict__ node, float* __restrict__ P1, float* __restrict__ P2,
    float* __restrict__ G1, float* __restrict__ G2) {
  __shared__ __align__(16) float ns[4][D_EMB];
  const int j = threadIdx.x;
  const int row0 = blockIdx.x * 4;
  float acc[4];
  const float bj = b[j];
#pragma unroll
  for (int r = 0; r < 4; r++) acc[r] = bj;
  const float* xr = x + (size_t)row0 * D_IN;
  for (int k = 0; k < D_IN; k += 4) {
    const float w0 = W[(k + 0) * D_EMB + j];
    const float w1 = W[(k + 1) * D_EMB + j];
    const float w2 = W[(k + 2) * D_EMB + j];
    const float w3 = W[(k + 3) * D_EMB + j];
#pragma unroll
    for (int r = 0; r < 4; r++) {
      const float4 xv = *reinterpret_cast<const float4*>(xr + (size_t)r * D_IN + k);
      acc[r] = fmaf(xv.x, w0, acc[r]);
      acc[r] = fmaf(xv.y, w1, acc[r]);
      acc[r] = fmaf(xv.z, w2, acc[r]);
      acc[r] = fmaf(xv.w, w3, acc[r]);
    }
  }
#pragma unroll
  for (int r = 0; r < 4; r++) {
    const float v = fmaxf(acc[r], 0.f);
    node[(size_t)(row0 + r) * D_EMB + j] = v;
    ns[r][j] = v;
  }
  __syncthreads();
  {
    const int r = j >> 6, h = j & 63;   // 4 rows x 64 h = 256 threads
    float a1 = 0.f, a2 = 0.f;
    for (int k = 0; k < D_EMB; k += 4) {
      const float4 nv = *reinterpret_cast<const float4*>(&ns[r][k]);
      a1 = fmaf(nv.x, W1a[(k + 0) * 64 + h], a1);
      a1 = fmaf(nv.y, W1a[(k + 1) * 64 + h], a1);
      a1 = fmaf(nv.z, W1a[(k + 2) * 64 + h], a1);
      a1 = fmaf(nv.w, W1a[(k + 3) * 64 + h], a1);
      a2 = fmaf(nv.x, W1a[(D_EMB + k + 0) * 64 + h], a2);
      a2 = fmaf(nv.y, W1a[(D_EMB + k + 1) * 64 + h], a2);
      a2 = fmaf(nv.z, W1a[(D_EMB + k + 2) * 64 + h], a2);
      a2 = fmaf(nv.w, W1a[(D_EMB + k + 3) * 64 + h], a2);
    }
    P1[(size_t)(row0 + r) * 64 + h] = a1;
    P2[(size_t)(row0 + r) * 64 + h] = a2;
  }
  if (j < 64) {
    const int r = j >> 4, h = j & 15;
    const int n = row0 + r;
    float g1 = 0.f, g2 = 0.f;
#pragma unroll
    for (int k = 0; k < 4; k++) {
      const float c = coords[(size_t)n * 4 + k];
      g1 = fmaf(c, W1g[k * 16 + h], g1);
      g2 = fmaf(c, W1g[(4 + k) * 16 + h], g2);
    }
    G1[(size_t)n * 16 + h] = g1;
    G2[(size_t)n * 16 + h] = g2;
  }
}

// ======== per-edge scalar weight (analytic edge structure) ========
__global__ __launch_bounds__(256) void k_edge(
    const float* __restrict__ P1, const float* __restrict__ P2,
    const float* __restrict__ G1, const float* __restrict__ G2,
    const float* __restrict__ b1a, const float* __restrict__ W2a, const float* __restrict__ b2a,
    const float* __restrict__ b1g, const float* __restrict__ W2g, const float* __restrict__ b2g,
    const float* __restrict__ W1f, const float* __restrict__ b1f,
    const float* __restrict__ W2f, const float* __restrict__ b2f,
    float* __restrict__ wE) {
  const int e = blockIdx.x * 256 + threadIdx.x;
  int s, dn;
  if (e < E_NUM) {
    const int t = e >> 6, o = e & 63;
    s = t; dn = T_NUM + ((13 * t + o) & 1023);
  } else {
    const int e2 = e - E_NUM;
    const int t = e2 >> 6, o = e2 & 63;
    s = T_NUM + ((13 * t + o) & 1023); dn = t;
  }
  const float4* p1 = (const float4*)(P1 + (size_t)s * 64);
  const float4* p2 = (const float4*)(P2 + (size_t)dn * 64);
  const float4* b1 = (const float4*)b1a;
  const float4* w2 = (const float4*)W2a;
  float a1 = b2a[0];
#pragma unroll
  for (int i = 0; i < 16; i++) {
    const float4 pa = p1[i], pb = p2[i], bb = b1[i], ww = w2[i];
    a1 += fmaxf(pa.x + pb.x + bb.x, 0.f) * ww.x + fmaxf(pa.y + pb.y + bb.y, 0.f) * ww.y +
          fmaxf(pa.z + pb.z + bb.z, 0.f) * ww.z + fmaxf(pa.w + pb.w + bb.w, 0.f) * ww.w;
  }
  const float4* g1 = (const float4*)(G1 + (size_t)s * 16);
  const float4* g2 = (const float4*)(G2 + (size_t)dn * 16);
  const float4* bg = (const float4*)b1g;
  const float4* wg = (const float4*)W2g;
  float a2 = b2g[0];
#pragma unroll
  for (int i = 0; i < 4; i++) {
    const float4 pa = g1[i], pb = g2[i], bb = bg[i], ww = wg[i];
    a2 += fmaxf(pa.x + pb.x + bb.x, 0.f) * ww.x + fmaxf(pa.y + pb.y + bb.y, 0.f) * ww.y +
          fmaxf(pa.z + pb.z + bb.z, 0.f) * ww.z + fmaxf(pa.w + pb.w + bb.w, 0.f) * ww.w;
  }
  float acc = b2f[0];
#pragma unroll
  for (int jj = 0; jj < 8; jj++) {
    const float h = fmaxf(a1 * W1f[jj] + a2 * W1f[8 + jj] + b1f[jj], 0.f);
    acc = fmaf(h, W2f[jj], acc);
  }
  wE[e] = acc;
}

// ======== fused: msg (analytic adjacency) + out GEMM + row norms (4 rows) ==
__global__ __launch_bounds__(256) void k_msg_out(
    const float* __restrict__ wE, const float* __restrict__ node,
    const float* __restrict__ Wn, const float* __restrict__ Wm,
    const float* __restrict__ bo, float* __restrict__ outE, float* __restrict__ nrm) {
  __shared__ __align__(16) float ms[4][D_EMB];
  __shared__ float wsh[4][64];
  __shared__ int ssh[4][64];
  __shared__ float redn[4][4];
  const int j = threadIdx.x;
  const int lane = j & 63, wid = j >> 6;
  const int row0 = blockIdx.x * 4;
  {
    const int r = j >> 6, o = j & 63;   // 256 threads = 4 rows x 64 edges
    const int n = row0 + r;
    int e, src;
    if (n < T_NUM) {              // tracklet: incoming reversed edges, contiguous
      e = E_NUM + n * 64 + o;
      src = T_NUM + ((13 * n + o) & 1023);
    } else {                      // det d: incoming from tracklet t=709(d-o)
      const int d = n - T_NUM;
      const int t = (709 * (d - o)) & 1023;
      e = t * 64 + o;
      src = t;
    }
    wsh[r][o] = wE[e];
    ssh[r][o] = src;
  }
  __syncthreads();
#pragma unroll 1
  for (int r = 0; r < 4; r++) {
    float acc = 0.f;
#pragma unroll 4
    for (int i = 0; i < 64; i++)
      acc = fmaf(wsh[r][i], node[(size_t)ssh[r][i] * D_EMB + j], acc);
    ms[r][j] = acc;
  }
  __syncthreads();
  float acc[4];
  const float bj = bo[j];
#pragma unroll
  for (int r = 0; r < 4; r++) acc[r] = bj;
  const float* nrow = node + (size_t)row0 * D_EMB;
  for (int k = 0; k < D_EMB; k += 4) {
    const float wn0 = Wn[(k + 0) * D_EMB + j], wm0 = Wm[(k + 0) * D_EMB + j];
    const float wn1 = Wn[(k + 1) * D_EMB + j], wm1 = Wm[(k + 1) * D_EMB + j];
    const float wn2 = Wn[(k + 2) * D_EMB + j], wm2 = Wm[(k + 2) * D_EMB + j];
    const float wn3 = Wn[(k + 3) * D_EMB + j], wm3 = Wm[(k + 3) * D_EMB + j];
#pragma unroll
    for (int r = 0; r < 4; r++) {
      const float4 nv = *reinterpret_cast<const float4*>(nrow + (size_t)r * D_EMB + k);
      const float4 mv = *reinterpret_cast<const float4*>(&ms[r][k]);
      acc[r] = fmaf(nv.x, wn0, acc[r]); acc[r] = fmaf(mv.x, wm0, acc[r]);
      acc[r] = fmaf(nv.y, wn1, acc[r]); acc[r] = fmaf(mv.y, wm1, acc[r]);
      acc[r] = fmaf(nv.z, wn2, acc[r]); acc[r] = fmaf(mv.z, wm2, acc[r]);
      acc[r] = fmaf(nv.w, wn3, acc[r]); acc[r] = fmaf(mv.w, wm3, acc[r]);
    }
  }
#pragma unroll
  for (int r = 0; r < 4; r++) {
    acc[r] = fmaxf(acc[r], 0.f);
    outE[(size_t)(row0 + r) * D_EMB + j] = acc[r];
  }
#pragma unroll
  for (int r = 0; r < 4; r++) {
    float sq = acc[r] * acc[r];
#pragma unroll
    for (int o = 32; o > 0; o >>= 1) sq += __shfl_down(sq, o, 64);
    if (lane == 0) redn[wid][r] = sq;
  }
  __syncthreads();
  if (j < 4)
    nrm[row0 + j] = sqrtf(redn[0][j] + redn[1][j] + redn[2][j] + redn[3][j]);
}

// ======== affinity -> banded kernel buffers + pad zeroing (no memset) ======
// t' = 13*t mod 1024 ; row t' window covers cols [t', t'+63]
// Kbp[t'][  (t'&3) + m        ] = K   ; KTfp[d][ (s0&3) + 63-m ] = K
// Each row has exactly 4 pad slots; thread o<4 of the matching row zeros one.
__global__ __launch_bounds__(256) void k_aff(
    const float* __restrict__ outE, const float* __restrict__ nrm,
    const float* __restrict__ cov,
    const float* __restrict__ W1c, const float* __restrict__ b1c,
    const float* __restrict__ W2c, const float* __restrict__ b2c,
    float* __restrict__ Kbp, float* __restrict__ KTfp) {
  const int e = blockIdx.x * 256 + threadIdx.x;
  const int t = e >> 6, o = e & 63;
  const int s = t;
  const int d = (13 * t + o) & 1023;
  const int dn = T_NUM + d;
  const float4* oa = (const float4*)(outE + (size_t)s * D_EMB);
  const float4* ob = (const float4*)(outE + (size_t)dn * D_EMB);
  float dot = 0.f;
#pragma unroll 8
  for (int i = 0; i < 64; i++) {
    const float4 a = oa[i], bq = ob[i];
    dot += a.x * bq.x + a.y * bq.y + a.z * bq.z + a.w * bq.w;
  }
  const float cosv = dot / fmaxf(nrm[s] * nrm[dn], 1e-6f);
  const float4 A = ((const float4*)cov)[s];
  const float4 B = ((const float4*)cov)[dn];
  const float ltx = fmaxf(A.x, B.x), lty = fmaxf(A.y, B.y);
  const float rbx = fminf(A.z, B.z), rby = fminf(A.w, B.w);
  const float wx = fmaxf(rbx - ltx, 0.f), wy = fmaxf(rby - lty, 0.f);
  const float inter = wx * wy;
  const float areaA = (A.z - A.x) * (A.w - A.y);
  const float areaB = (B.z - B.x) * (B.w - B.y);
  const float iou = inter / (areaA + areaB - inter + 1e-9f);
  float aff = b2c[0];
#pragma unroll
  for (int jj = 0; jj < 8; jj++) {
    const float h = fmaxf(cosv * W1c[jj] + iou * W1c[8 + jj] + b1c[jj], 0.f);
    aff = fmaf(h, W2c[jj], aff);
  }
  const float Kv = __expf(aff * 5.0f);
  const int tp = (13 * s) & 1023;
  const int m = (d - tp) & 1023;            // == o
  const int s0 = (d + 961) & 1023;          // col-window start (d-63 mod 1024)
  Kbp[tp * 68 + (tp & 3) + m] = Kv;
  KTfp[d * 68 + (s0 & 3) + 63 - m] = Kv;
  if (o < 4) {
    const int pr = (o < (tp & 3)) ? o : o + 64;   // Kbp row-tp pad slots
    Kbp[tp * 68 + pr] = 0.f;
    const int pc = (o < (s0 & 3)) ? o : o + 64;   // KTfp row-d pad slots
    KTfp[d * 68 + pc] = 0.f;
  }
}

// ======== Sinkhorn: 256 thr x (4 rows + 4 cols). Row-K bf16 in registers
// (256-thr blocks get big VGPR budgets, cf. spills at 512/1024 thr);
// col-K streamed f32 from global (L2-resident after iter 1). ========
__device__ __forceinline__ unsigned bf16r(float x) {
  const unsigned u = __float_as_uint(x);
  return (u + 0x7fffu + ((u >> 16) & 1u)) >> 16;  // RNE
}
__device__ __forceinline__ float bflo(unsigned p) { return __uint_as_float(p << 16); }
__device__ __forceinline__ float bfhi(unsigned p) { return __uint_as_float(p & 0xffff0000u); }

__global__ __launch_bounds__(256, 1) void k_sinkhorn(
    const float* __restrict__ Kbp, const float* __restrict__ KTfp,
    float* __restrict__ ug, float* __restrict__ vg) {
  __shared__ __align__(16) float u_lds[1092];   // replicated: [1024+i]=[i], i<68
  __shared__ __align__(16) float v_lds[1092];
  __shared__ __align__(16) float red_u[4];
  __shared__ __align__(16) float red_v[4];
  const int tid = threadIdx.x;                  // 0..255
  const int lane = tid & 63, wid = tid >> 6;
  unsigned kb[4][34];                           // 4 rows x 64 bf16 (+4 pad)
#pragma unroll
  for (int r = 0; r < 4; r++) {
    const float4* s1 = (const float4*)(Kbp + (size_t)(tid + 256 * r) * 68);
#pragma unroll
    for (int c = 0; c < 17; c++) {
      const float4 f = s1[c];
      kb[r][2 * c]     = bf16r(f.x) | (bf16r(f.y) << 16);
      kb[r][2 * c + 1] = bf16r(f.z) | (bf16r(f.w) << 16);
    }
  }
  float u_own[4] = {1.f, 1.f, 1.f, 1.f};
  float v_own[4] = {1.f, 1.f, 1.f, 1.f};
  float u_sl = 1.f, v_sl = 1.f;
#pragma unroll
  for (int r = 0; r < 4; r++) v_lds[tid + 256 * r] = 1.f;
  if (tid < 68) v_lds[1024 + tid] = 1.f;
  if (tid < 4) red_v[tid] = 256.f;
  const float slack = 0.36787944117144233f;     // exp(SLACK*LAM) = exp(-1)
  __syncthreads();
#pragma unroll 1
  for (int it = 0; it < 8; ++it) {
    // ---- row phase: s_i = K_i . v_window + slack*v_sl
    const float4* vq = (const float4*)v_lds;
    float sv[4];
#pragma unroll
    for (int r = 0; r < 4; r++) {
      const int qa = (tid + 256 * r) >> 2;      // (tp&3)==(tid&3) for all r
      float a0 = 0.f, a1 = 0.f;
#pragma unroll
      for (int c = 0; c < 17; c++) {
        const float4 v4 = vq[qa + c];
        const unsigned p0 = kb[r][2 * c], p1 = kb[r][2 * c + 1];
        a0 = fmaf(bflo(p0), v4.x, a0); a0 = fmaf(bfhi(p0), v4.y, a0);
        a1 = fmaf(bflo(p1), v4.z, a1); a1 = fmaf(bfhi(p1), v4.w, a1);
      }
      sv[r] = a0 + a1 + slack * v_sl;
    }
    const float sumv = red_v[0] + red_v[1] + red_v[2] + red_v[3];
    float usum = 0.f;
#pragma unroll
    for (int r = 0; r < 4; r++) {
      const float un = u_own[r] / (u_own[r] * sv[r] + 1e-9f);
      u_own[r] = un; u_lds[tid + 256 * r] = un; usum += un;
    }
    u_sl = u_sl / (u_sl * slack * (sumv + v_sl) + 1e-9f);
    if (tid < 68) u_lds[1024 + tid] = u_own[0];
#pragma unroll
    for (int o = 32; o > 0; o >>= 1) usum += __shfl_down(usum, o, 64);
    if (lane == 0) red_u[wid] = usum;
    __syncthreads();
    // ---- col phase: t_j = KT_j . u_window + slack*u_sl  (K streamed f32)
    const float4* uq = (const float4*)u_lds;
    float tv[4];
#pragma unroll
    for (int r = 0; r < 4; r++) {
      const int d = tid + 256 * r;
      const int qc = ((d + 961) & 1023) >> 2;
      const float4* kt = (const float4*)(KTfp + (size_t)d * 68);
      float a0 = 0.f, a1 = 0.f;
#pragma unroll
      for (int c = 0; c < 17; c++) {
        const float4 kk = kt[c];
        const float4 u4 = uq[qc + c];
        a0 = fmaf(kk.x, u4.x, a0); a0 = fmaf(kk.y, u4.y, a0);
        a1 = fmaf(kk.z, u4.z, a1); a1 = fmaf(kk.w, u4.w, a1);
      }
      tv[r] = a0 + a1 + slack * u_sl;
    }
    const float sumu = red_u[0] + red_u[1] + red_u[2] + red_u[3];
    float vsum = 0.f;
#pragma unroll
    for (int r = 0; r < 4; r++) {
      const float vn = v_own[r] / (v_own[r] * tv[r] + 1e-9f);
      v_own[r] = vn; v_lds[tid + 256 * r] = vn; vsum += vn;
    }
    v_sl = v_sl / (v_sl * slack * (sumu + u_sl) + 1e-9f);
    if (tid < 68) v_lds[1024 + tid] = v_own[0];
#pragma unroll
    for (int o = 32; o > 0; o >>= 1) vsum += __shfl_down(vsum, o, 64);
    if (lane == 0) red_v[wid] = vsum;
    __syncthreads();
  }
#pragma unroll
  for (int r = 0; r < 4; r++) {
    ug[tid + 256 * r] = u_own[r];   // indexed by t' (permuted row space)
    vg[tid + 256 * r] = v_own[r];   // indexed by d
  }
}

// ======== dense final write + fused gt copy + scalars ========
__global__ __launch_bounds__(256) void k_final(
    const float* __restrict__ Kbp, const float* __restrict__ ug,
    const float* __restrict__ vg, const float* __restrict__ gt,
    float* __restrict__ out) {
  const int t = blockIdx.x;
  const int tp = (13 * t) & 1023;
  const float u = ug[tp];
  const float* krow = Kbp + (size_t)tp * 68 + (tp & 3);
  const int d0 = threadIdx.x * 4;
  const float4 v4 = ((const float4*)vg)[threadIdx.x];
  float4 o4;
  const int m0 = (d0 - tp) & 1023;
  const int m1 = (d0 + 1 - tp) & 1023;
  const int m2 = (d0 + 2 - tp) & 1023;
  const int m3 = (d0 + 3 - tp) & 1023;
  o4.x = (m0 < 64) ? u * krow[m0] * v4.x : 0.f;
  o4.y = (m1 < 64) ? u * krow[m1] * v4.y : 0.f;
  o4.z = (m2 < 64) ? u * krow[m2] * v4.z : 0.f;
  o4.w = (m3 < 64) ? u * krow[m3] * v4.w : 0.f;
  ((float4*)out)[(size_t)t * 256 + threadIdx.x] = o4;
  const float4 g4 = ((const float4*)gt)[(size_t)t * 256 + threadIdx.x];
  ((float4*)out)[(size_t)(T_NUM + t) * 256 + threadIdx.x] = g4;
  if (t == 0 && threadIdx.x == 0) {
    out[(size_t)2 * T_NUM * DET_NUM] = 1024.0f;      // det_num
    out[(size_t)2 * T_NUM * DET_NUM + 1] = 1024.0f;  // tracklet_num
  }
}

extern "C" void kernel_launch(void* const* d_in, const int* in_sizes, int n_in,
                              void* d_out, int out_size, void* d_ws, size_t ws_size,
                              hipStream_t stream) {
  const float* x      = (const float*)d_in[0];
  const float* coords = (const float*)d_in[1];
  const float* cov    = (const float*)d_in[2];
  const float* gt     = (const float*)d_in[3];
  const float* W_enc  = (const float*)d_in[5];
  const float* b_enc  = (const float*)d_in[6];
  const float* W1a    = (const float*)d_in[7];
  const float* b1a    = (const float*)d_in[8];
  const float* W2a    = (const float*)d_in[9];
  const float* b2a    = (const float*)d_in[10];
  const float* W1g    = (const float*)d_in[11];
  const float* b1g    = (const float*)d_in[12];
  const float* W2g    = (const float*)d_in[13];
  const float* b2g    = (const float*)d_in[14];
  const float* W1f    = (const float*)d_in[15];
  const float* b1f    = (const float*)d_in[16];
  const float* W2f    = (const float*)d_in[17];
  const float* b2f    = (const float*)d_in[18];
  const float* Wn     = (const float*)d_in[19];
  const float* Wm     = (const float*)d_in[20];
  const float* bo     = (const float*)d_in[21];
  const float* W1c    = (const float*)d_in[22];
  const float* b1c    = (const float*)d_in[23];
  const float* W2c    = (const float*)d_in[24];
  const float* b2c    = (const float*)d_in[25];

  char* ws = (char*)d_ws;
  size_t off = 0;
  auto alloc = [&](size_t bytes) {
    char* p = ws + off;
    off = (off + bytes + 255) & ~(size_t)255;
    return p;
  };
  float* node  = (float*)alloc((size_t)N_NODES * D_EMB * 4);
  float* P1    = (float*)alloc((size_t)N_NODES * 64 * 4);
  float* P2    = (float*)alloc((size_t)N_NODES * 64 * 4);
  float* G1    = (float*)alloc((size_t)N_NODES * 16 * 4);
  float* G2    = (float*)alloc((size_t)N_NODES * 16 * 4);
  float* wE    = (float*)alloc((size_t)TWO_E * 4);
  float* outE  = (float*)alloc((size_t)N_NODES * D_EMB * 4);
  float* nrm   = (float*)alloc((size_t)N_NODES * 4);
  float* Kbp   = (float*)alloc((size_t)1024 * 68 * 4);
  float* KTfp  = (float*)alloc((size_t)1024 * 68 * 4);
  float* ug    = (float*)alloc(1024 * 4);
  float* vg    = (float*)alloc(1024 * 4);
  float* out   = (float*)d_out;

  k_enc_pg<<<N_NODES / 4, 256, 0, stream>>>(x, W_enc, b_enc, coords, W1a, W1g,
                                            node, P1, P2, G1, G2);
  k_edge<<<TWO_E / 256, 256, 0, stream>>>(P1, P2, G1, G2, b1a, W2a, b2a,
                                          b1g, W2g, b2g, W1f, b1f, W2f, b2f, wE);
  k_msg_out<<<N_NODES / 4, 256, 0, stream>>>(wE, node, Wn, Wm, bo, outE, nrm);
  k_aff<<<E_NUM / 256, 256, 0, stream>>>(outE, nrm, cov, W1c, b1c, W2c, b2c,
                                         Kbp, KTfp);
  k_sinkhorn<<<1, 256, 0, stream>>>(Kbp, KTfp, ug, vg);
  k_final<<<T_NUM, 256, 0, stream>>>(Kbp, ug, vg, gt, out);
}